// Round 8
// baseline (1267.667 us; speedup 1.0000x reference)
//
#include <hip/hip_runtime.h>

// NLReader bidirectional LSTM, MI355X — persistent scan, fence-free MALL relay.
//
// Round-16 = EXACT round-13 (930 us fused, best measured) + ONE change:
//  * xq (precomputed x-gate) loads become an ISSUE-ONLY prefetch in the step
//    tail (no s_waitcnt in the issuing asm node). They drain at the NEXT
//    step's poll (the compiler inserts vmcnt(0) before using the polled
//    flag; vmcnt retires in order so the prefetch completes there) and are
//    double-covered by the h-fetch's explicit vmcnt(0). A sched_barrier(0)
//    after the h-fetch pins the first register use of the prefetched values
//    below that wait (rule: hipcc may hoist register-only ops past inline-asm
//    waitcnt). Effect: the tail's dedicated xq vmcnt(0) MALL round-trip
//    leaves the serial chain; its latency hides under tail-stores + loop +
//    poll + h-fetch issue.
//  * Round-15b's changes REVERTED: tight poll back to r13's fa/fb (bundle
//    regressed +0.65 us/step; un-exonerated), xq no longer shares the
//    h-fetch wait with zero head start.
//  * Everything else verbatim round-13: 128 scan blocks x 8 units, wave-
//    matched flags, sc1 MALL h relay + one-asm-node h-fetch, f32 c-state in
//    registers, fused 1024-block xproj (sc1 stores + u16 group flags),
//    emb_gather prepass (also zeroes the 266 KB scan region).
//
// Block (dir=bid>>6, kb=bid&63) owns 8 hidden units as 32 permuted gate cols:
//   tile t4 in {0,1}, lane col c in [0,16): gate g = c&3, unit jj = 2*(c>>2)+t4
//   orig Wih/Whh row = g*512 + kb*8 + jj.

typedef float  f32x4  __attribute__((ext_vector_type(4)));
typedef __bf16 bf16x8 __attribute__((ext_vector_type(8)));
typedef __bf16 bf16;

#define HB_OFF   ((size_t)0)        // 4 x [64 x 512] bf16 = 262144 B
#define FLAG_OFF ((size_t)262144)   // 512 x u32 = 2048 B
#define XF_OFF   ((size_t)264192)   // 1024 x u16 xproj group flags (new path)
                                    // (same bytes are ZROW in the legacy path)
#define WS_ZERO_BYTES ((size_t)266240)
#define XP_OFF   ((size_t)266240)                 // 128 blk*128 s*2048 f32
#define XP_BYTES ((size_t)134217728)
#define EBF_OFF  (XP_OFF + XP_BYTES)              // 8192 rows * 512 bf16
#define EBF_BYTES ((size_t)8388608)
#define WS_NEED  (EBF_OFF + EBF_BYTES)            // 142,872,576 B (unchanged)

__device__ __forceinline__ float sigmoidf_(float x) {
    return 1.0f / (1.0f + __expf(-x));
}
__device__ __forceinline__ float tanhf_(float x) {
    return 2.0f * sigmoidf_(2.0f * x) - 1.0f;
}
__device__ __forceinline__ bf16x8 cvt8(const float* p) {
    float4 a = *(const float4*)p;
    float4 b = *(const float4*)(p + 4);
    bf16x8 r;
    r[0] = (bf16)a.x; r[1] = (bf16)a.y; r[2] = (bf16)a.z; r[3] = (bf16)a.w;
    r[4] = (bf16)b.x; r[5] = (bf16)b.y; r[6] = (bf16)b.z; r[7] = (bf16)b.w;
    return r;
}
__device__ __forceinline__ bf16x8 cvt8v(uint4 u0, uint4 u1) {
    float4 a = __builtin_bit_cast(float4, u0);
    float4 b = __builtin_bit_cast(float4, u1);
    bf16x8 r;
    r[0] = (bf16)a.x; r[1] = (bf16)a.y; r[2] = (bf16)a.z; r[3] = (bf16)a.w;
    r[4] = (bf16)b.x; r[5] = (bf16)b.y; r[6] = (bf16)b.z; r[7] = (bf16)b.w;
    return r;
}
__device__ __forceinline__ void store4_sc1(float* p, f32x4 v) {
    asm volatile("global_store_dwordx4 %0, %1, off sc1"
                 :: "v"((unsigned long long)p), "v"(v) : "memory");
}
__device__ __forceinline__ void wait_xf(unsigned long long a) {
    for (;;) {
        unsigned v;
        asm volatile("global_load_ushort %0, %1, off sc1\n\t"
                     "s_waitcnt vmcnt(0)"
                     : "=&v"(v) : "v"(a) : "memory");
        if (v != 0) break;
        __builtin_amdgcn_s_sleep(2);
    }
}

__global__ __launch_bounds__(256) void init_ws_legacy(unsigned long long* __restrict__ w) {
    const size_t i = (size_t)blockIdx.x * 256 + threadIdx.x;
    if (i < WS_ZERO_BYTES / 8) w[i] = 0ull;
}

// ---- pre-pass: gather + f32->bf16 embedding rows; pad rows zeroed.
// Blocks 0..129 also zero the 266 KB scan region (hbuf + relay flags + XF).
__global__ __launch_bounds__(256) void emb_gather(
    const int* __restrict__ data, const float* __restrict__ table,
    bf16* __restrict__ ebf, unsigned long long* __restrict__ wz)
{
    const int bid = blockIdx.x, tid = threadIdx.x;
    if (bid < 130) {                                // 130*256*8 = 266240 B
        wz[(size_t)bid * 256 + tid] = 0ull;
    }
    const int wave = tid >> 6, lane = tid & 63;
    const int rr = bid * 4 + wave;                  // 0..8191 = t*64+b
    const int qv = data[rr];
    bf16x8 v;
    if (qv >= 0) {
        v = cvt8(table + (size_t)qv * 512 + lane * 8);
    } else {
#pragma unroll
        for (int i = 0; i < 8; ++i) v[i] = (bf16)0.f;
    }
    *(bf16x8*)(ebf + (size_t)rr * 512 + lane * 8) = v;
}

// ---- fused kernel: scan role (bid<128) + xproj role (bid>=128) ----
__global__ __launch_bounds__(256, 1) void fused_scan(
    const float* __restrict__ mask,
    const float* __restrict__ whh_f, const float* __restrict__ whh_b,
    const float* __restrict__ bih_f, const float* __restrict__ bhh_f,
    const float* __restrict__ bih_b, const float* __restrict__ bhh_b,
    const float* __restrict__ wih_f, const float* __restrict__ wih_b,
    const bf16* __restrict__ ebf,
    float* __restrict__ xp,
    bf16* __restrict__ hbuf,
    unsigned* __restrict__ flags,
    unsigned short* __restrict__ xf,
    float* __restrict__ out)
{
    __shared__ bf16 sM[4096 * 8];      // 64 KB; scan role uses first 32 KB

    const int tid = threadIdx.x, bid = blockIdx.x;
    const int wave = tid >> 6, lane = tid & 63;
    const int c = lane & 15, q = lane >> 4;

    if (bid >= 128) {
        // ================= xproj role (verbatim round-13) =================
        const int xbid = bid - 128;
        const int dir = xbid >> 9, cc = (xbid >> 4) & 31, sh = xbid & 15;
        const float* wih = dir ? wih_b : wih_f;

        for (int e = tid; e < 4096; e += 256) {
            const int ec = e & 15, eq = (e >> 4) & 3, et = (e >> 6) & 3, ekc = e >> 8;
            const int kbx = 2 * cc + (et >> 1), t4x = et & 1;
            const size_t orig = (size_t)((ec & 3) * 512 + kbx * 8 + 2 * (ec >> 2) + t4x);
            *(bf16x8*)(&sM[e * 8]) = cvt8(&wih[orig * 512 + ekc * 32 + eq * 8]);
        }
        __syncthreads();

        const int hrow = 16 * wave + c;
        const f32x4 zz = {0.f, 0.f, 0.f, 0.f};
        const size_t flin = (size_t)wave * 512 + (q * 16 + c) * 8;

        for (int s0 = 0; s0 < 8; ++s0) {
            const int s = sh * 8 + s0;
            const int tt = dir ? (127 - s) : s;
            const bf16* arow = ebf + (size_t)(tt * 64 + hrow) * 512;
            uint4 af[16];
#pragma unroll
            for (int kc = 0; kc < 16; ++kc)
                af[kc] = *(const uint4*)(arow + kc * 32 + q * 8);

            f32x4 acc0 = zz, acc1 = zz, acc2 = zz, acc3 = zz;
#pragma unroll
            for (int kc = 0; kc < 16; ++kc) {
                const bf16x8 a = __builtin_bit_cast(bf16x8, af[kc]);
                acc0 = __builtin_amdgcn_mfma_f32_16x16x32_bf16(
                    a, *(const bf16x8*)(&sM[(kc * 256 +   0 + q * 16 + c) * 8]), acc0, 0, 0, 0);
                acc1 = __builtin_amdgcn_mfma_f32_16x16x32_bf16(
                    a, *(const bf16x8*)(&sM[(kc * 256 +  64 + q * 16 + c) * 8]), acc1, 0, 0, 0);
                acc2 = __builtin_amdgcn_mfma_f32_16x16x32_bf16(
                    a, *(const bf16x8*)(&sM[(kc * 256 + 128 + q * 16 + c) * 8]), acc2, 0, 0, 0);
                acc3 = __builtin_amdgcn_mfma_f32_16x16x32_bf16(
                    a, *(const bf16x8*)(&sM[(kc * 256 + 192 + q * 16 + c) * 8]), acc3, 0, 0, 0);
            }
            const size_t r0 = ((size_t)(dir * 64 + 2 * cc)     * 128 + s) * 2048 + flin;
            const size_t r1 = ((size_t)(dir * 64 + 2 * cc + 1) * 128 + s) * 2048 + flin;
            store4_sc1(&xp[r0],     acc0);      // kb=2cc,  t4=0
            store4_sc1(&xp[r0 + 4], acc1);      // kb=2cc,  t4=1
            store4_sc1(&xp[r1],     acc2);      // kb=2cc+1,t4=0
            store4_sc1(&xp[r1 + 4], acc3);      // kb=2cc+1,t4=1
        }
        __builtin_amdgcn_s_waitcnt(0x0F70);     // this wave's sc1 stores acked
        __syncthreads();                        // all 4 waves acked
        if (tid == 0) {
            const unsigned long long fa =
                (unsigned long long)&xf[(dir * 32 + cc) * 16 + sh];
            asm volatile("global_store_short %0, %1, off sc1"
                         :: "v"(fa), "v"(1u) : "memory");
        }
        return;
    }

    // ========= scan role (round-13 + issue-only xq prefetch in tail) ========
    const int dir = bid >> 6, kb = bid & 63;
    const int g = c & 3;

    const float* whh = dir ? whh_b : whh_f;
    const float* bih = dir ? bih_b : bih_f;
    const float* bhh = dir ? bhh_b : bhh_f;

    for (int e = tid; e < 2048; e += 256) {
        const int ec = e & 15, eq = (e >> 4) & 3, et = (e >> 6) & 1, ekc = e >> 7;
        const size_t orig = (size_t)((ec & 3) * 512 + kb * 8 + 2 * (ec >> 2) + et);
        *(bf16x8*)(&sM[e * 8]) = cvt8(&whh[orig * 512 + ekc * 32 + eq * 8]);
    }
    float bias_v[2];
#pragma unroll
    for (int t4 = 0; t4 < 2; ++t4) {
        const int orig = g * 512 + kb * 8 + 2 * (c >> 2) + t4;
        bias_v[t4] = bih[orig] + bhh[orig];
    }

    float cst[2][4] = {{0.f, 0.f, 0.f, 0.f}, {0.f, 0.f, 0.f, 0.f}};
    const int hrow = 16 * wave + c;
    const int myflag = dir * 256 + wave * 64 + kb;
    const int fidx   = dir * 256 + wave * 64 + lane;
    const f32x4 zz = {0.f, 0.f, 0.f, 0.f};
    __syncthreads();                    // sM(=sW) ready; no syncs after this

    // xproj group-flag base for this block's (dir, cc=kb>>1)
    const unsigned long long xfb =
        (unsigned long long)(xf + ((size_t)(dir * 32 + (kb >> 1)) * 16));

    // prologue: confirm xp group 0 resident; ISSUE step-0 xq prefetch (no
    // wait — drained by the first poll / h-fetch vmcnt); load step-0 mask.
    const float* xpb = xp + (size_t)bid * 128 * 2048
                          + (size_t)wave * 512 + (q * 16 + c) * 8;
    wait_xf(xfb);
    uint4 xu0, xu1;
    {
        const unsigned long long xa = (unsigned long long)xpb;
        asm volatile("global_load_dwordx4 %0, %2, off sc1\n\t"
                     "global_load_dwordx4 %1, %2, off offset:16 sc1"
                     : "=&v"(xu0), "=&v"(xu1) : "v"(xa) : "memory");
    }
    float4 mv;
    {
        const int tt0 = dir ? 127 : 0;
        mv = *(const float4*)(&mask[tt0 * 64 + 16 * wave + 4 * q]);
    }

    for (int s = 0; s < 128; ++s) {
        const int tt = dir ? (127 - s) : s;

        // ---- wait: the 64 wave-matched producer waves completed step s-1.
        // (verbatim r13 fa/fb poll; its generated vmcnt(0) also drains the
        // xq prefetch issued in the previous tail)
        const unsigned tgt = (unsigned)s;
        unsigned fa = __hip_atomic_load(flags + fidx, __ATOMIC_RELAXED, __HIP_MEMORY_SCOPE_AGENT);
        unsigned fb = __hip_atomic_load(flags + fidx, __ATOMIC_RELAXED, __HIP_MEMORY_SCOPE_AGENT);
        for (;;) {
            if (__all(fa >= tgt)) break;
            fa = fb;
            fb = __hip_atomic_load(flags + fidx, __ATOMIC_RELAXED, __HIP_MEMORY_SCOPE_AGENT);
        }
        __asm__ volatile("" ::: "memory");   // keep h-loads below the poll

        const bf16* hb = hbuf + (size_t)(dir * 2 + (s & 1)) * (64 * 512);
        bf16*       hw = hbuf + (size_t)(dir * 2 + ((s + 1) & 1)) * (64 * 512);

        // ---- h A-fragments: ONE asm node = 16 sc1 dwordx4 + vmcnt(0) ----
        const unsigned long long ha =
            (unsigned long long)hb + (unsigned)(hrow * 1024 + q * 16);
        uint4 af[16];
        asm volatile(
            "global_load_dwordx4 %0,  %16, off sc1\n\t"
            "global_load_dwordx4 %1,  %16, off offset:64   sc1\n\t"
            "global_load_dwordx4 %2,  %16, off offset:128  sc1\n\t"
            "global_load_dwordx4 %3,  %16, off offset:192  sc1\n\t"
            "global_load_dwordx4 %4,  %16, off offset:256  sc1\n\t"
            "global_load_dwordx4 %5,  %16, off offset:320  sc1\n\t"
            "global_load_dwordx4 %6,  %16, off offset:384  sc1\n\t"
            "global_load_dwordx4 %7,  %16, off offset:448  sc1\n\t"
            "global_load_dwordx4 %8,  %16, off offset:512  sc1\n\t"
            "global_load_dwordx4 %9,  %16, off offset:576  sc1\n\t"
            "global_load_dwordx4 %10, %16, off offset:640  sc1\n\t"
            "global_load_dwordx4 %11, %16, off offset:704  sc1\n\t"
            "global_load_dwordx4 %12, %16, off offset:768  sc1\n\t"
            "global_load_dwordx4 %13, %16, off offset:832  sc1\n\t"
            "global_load_dwordx4 %14, %16, off offset:896  sc1\n\t"
            "global_load_dwordx4 %15, %16, off offset:960  sc1\n\t"
            "s_waitcnt vmcnt(0)"
            : "=&v"(af[0]),  "=&v"(af[1]),  "=&v"(af[2]),  "=&v"(af[3]),
              "=&v"(af[4]),  "=&v"(af[5]),  "=&v"(af[6]),  "=&v"(af[7]),
              "=&v"(af[8]),  "=&v"(af[9]),  "=&v"(af[10]), "=&v"(af[11]),
              "=&v"(af[12]), "=&v"(af[13]), "=&v"(af[14]), "=&v"(af[15])
            : "v"(ha)
            : "memory");
        // rule-18 fence: no register use of the prefetched xu may hoist
        // above the vmcnt(0) inside the asm node.
        __builtin_amdgcn_sched_barrier(0);
        const float4 xq0 = __builtin_bit_cast(float4, xu0);
        const float4 xq1 = __builtin_bit_cast(float4, xu1);

        f32x4 acc0 = zz, acc1 = zz;
#pragma unroll
        for (int kc = 0; kc < 16; ++kc) {
            const bf16x8 a  = __builtin_bit_cast(bf16x8, af[kc]);
            const bf16x8 b0 = *(const bf16x8*)(&sM[(kc * 128 + q * 16 + c) * 8]);
            const bf16x8 b1 = *(const bf16x8*)(&sM[(kc * 128 + 64 + q * 16 + c) * 8]);
            acc0 = __builtin_amdgcn_mfma_f32_16x16x32_bf16(a, b0, acc0, 0, 0, 0);
            acc1 = __builtin_amdgcn_mfma_f32_16x16x32_bf16(a, b1, acc1, 0, 0, 0);
        }

        // ---- epilogue: C/D layout col=lane&15, row=q*4+r ----
        unsigned* hw32 = (unsigned*)hw;
        float hreg[4][2];
#pragma unroll
        for (int r = 0; r < 4; ++r) {
            const int b_ = 16 * wave + 4 * q + r;
            const float m = (&mv.x)[r];
            float hv01[2];
#pragma unroll
            for (int t4 = 0; t4 < 2; ++t4) {
                float v = (t4 ? acc1[r] : acc0[r])
                        + (t4 ? (&xq1.x)[r] : (&xq0.x)[r]) + bias_v[t4];
                const float v1 = __shfl_xor(v, 1);
                const float v2 = __shfl_xor(v, 2);
                const float v3 = __shfl_xor(v, 3);
                const float gi = (g == 0) ? v  : (g == 1) ? v1 : (g == 2) ? v2 : v3;
                const float gf = (g == 0) ? v1 : (g == 1) ? v  : (g == 2) ? v3 : v2;
                const float gG = (g == 0) ? v2 : (g == 1) ? v3 : (g == 2) ? v  : v1;
                const float go = (g == 0) ? v3 : (g == 1) ? v2 : (g == 2) ? v1 : v;
                const float cn = sigmoidf_(gf) * cst[t4][r] + sigmoidf_(gi) * tanhf_(gG);
                float hv       = sigmoidf_(go) * tanhf_(cn);
                cst[t4][r] = cn * m;
                hv *= m;
                hv01[t4] = hv;
            }
            hreg[r][0] = hv01[0]; hreg[r][1] = hv01[1];
            if (g == 0) {                   // packed 2xbf16 -> one u32 sc1 store
                const unsigned u =
                    (unsigned)__builtin_bit_cast(unsigned short, (bf16)hv01[0]) |
                    ((unsigned)__builtin_bit_cast(unsigned short, (bf16)hv01[1]) << 16);
                __hip_atomic_store(hw32 + b_ * 256 + kb * 4 + (c >> 2), u,
                                   __ATOMIC_RELAXED, __HIP_MEMORY_SCOPE_AGENT);
            }
        }

        // release: all h sc1-stores acked at MALL before flag store
        __asm__ volatile("" ::: "memory");
        __builtin_amdgcn_s_waitcnt(0x0F70);  // vmcnt(0)
        if (lane == 0)
            __hip_atomic_store(flags + myflag, (unsigned)(s + 1),
                               __ATOMIC_RELAXED, __HIP_MEMORY_SCOPE_AGENT);

        // ---- step tail: ISSUE-ONLY xq prefetch for s+1, then out-stores ----
        if (s < 127) {
            if (((s + 1) & 7) == 0)                 // new 8-step group
                wait_xf(xfb + (unsigned)(((s + 1) >> 3) * 2));
            const unsigned long long xa =
                (unsigned long long)(xpb + (size_t)(s + 1) * 2048);
            asm volatile("global_load_dwordx4 %0, %2, off sc1\n\t"
                         "global_load_dwordx4 %1, %2, off offset:16 sc1"
                         : "=&v"(xu0), "=&v"(xu1) : "v"(xa) : "memory");
        }
        if (g == 0) {
            const int j2 = dir * 512 + kb * 8 + 2 * (c >> 2);
#pragma unroll
            for (int r = 0; r < 4; ++r) {
                const int b_ = 16 * wave + 4 * q + r;
                float2 o2; o2.x = hreg[r][0]; o2.y = hreg[r][1];
                *(float2*)(&out[(size_t)(tt * 64 + b_) * 1024 + j2]) = o2;
            }
        }
        if (s < 127) {
            const int tt_n = dir ? (126 - s) : (s + 1);
            mv  = *(const float4*)(&mask[tt_n * 64 + 16 * wave + 4 * q]);
        }
    }
}

// ================= verbatim round-9 fallback (ws too small) =================
__global__ __launch_bounds__(256, 1) void lstm_scan_legacy(
    const int*   __restrict__ data,
    const float* __restrict__ mask,
    const float* __restrict__ table,
    const float* __restrict__ wih_f, const float* __restrict__ whh_f,
    const float* __restrict__ bih_f, const float* __restrict__ bhh_f,
    const float* __restrict__ wih_b, const float* __restrict__ whh_b,
    const float* __restrict__ bih_b, const float* __restrict__ bhh_b,
    bf16* __restrict__ hbuf,
    unsigned* __restrict__ flags,
    const float* __restrict__ zrow,
    float* __restrict__ out)
{
    __shared__ bf16 sW[2048 * 8];
    __shared__ bf16 sV[2048 * 8];

    const int tid = threadIdx.x, bid = blockIdx.x;
    const int dir = bid >> 6, kb = bid & 63;
    const int wave = tid >> 6, lane = tid & 63;
    const int c = lane & 15, q = lane >> 4, g = c & 3;

    const float* wih = dir ? wih_b : wih_f;
    const float* whh = dir ? whh_b : whh_f;
    const float* bih = dir ? bih_b : bih_f;
    const float* bhh = dir ? bhh_b : bhh_f;

    for (int e = tid; e < 2048; e += 256) {
        const int ec = e & 15, eq = (e >> 4) & 3, et = (e >> 6) & 1, ekc = e >> 7;
        const size_t orig = (size_t)((ec & 3) * 512 + kb * 8 + 2 * (ec >> 2) + et);
        const size_t off = orig * 512 + ekc * 32 + eq * 8;
        *(bf16x8*)(&sW[e * 8]) = cvt8(&whh[off]);
        *(bf16x8*)(&sV[e * 8]) = cvt8(&wih[off]);
    }
    float bias_v[2];
#pragma unroll
    for (int t4 = 0; t4 < 2; ++t4) {
        const int orig = g * 512 + kb * 8 + 2 * (c >> 2) + t4;
        bias_v[t4] = bih[orig] + bhh[orig];
    }

    float cst[2][4] = {{0.f, 0.f, 0.f, 0.f}, {0.f, 0.f, 0.f, 0.f}};
    const int hrow = 16 * wave + c;
    const int myflag = dir * 256 + kb * 4 + wave;
    const int fbase = dir * 256;
    const f32x4 zz = {0.f, 0.f, 0.f, 0.f};
    __syncthreads();

    uint4 xe[32];
    float4 mv;
    int qv_n;
    {
        const int tt0 = dir ? 127 : 0;
        const int qv0 = data[tt0 * 64 + hrow];
        mv = *(const float4*)(&mask[tt0 * 64 + 16 * wave + 4 * q]);
        const float* erow = (qv0 >= 0) ? (table + (size_t)qv0 * 512) : zrow;
#pragma unroll
        for (int kc = 0; kc < 16; ++kc) {
            xe[2 * kc]     = *(const uint4*)(erow + kc * 32 + q * 8);
            xe[2 * kc + 1] = *(const uint4*)(erow + kc * 32 + q * 8 + 4);
        }
        const int tt1 = dir ? 126 : 1;
        qv_n = data[tt1 * 64 + hrow];
    }

    for (int s = 0; s < 128; ++s) {
        const int tt = dir ? (127 - s) : s;

        f32x4 accx0 = zz, accx1 = zz;
#pragma unroll
        for (int kc = 0; kc < 16; ++kc) {
            const bf16x8 e  = cvt8v(xe[2 * kc], xe[2 * kc + 1]);
            const bf16x8 b0 = *(const bf16x8*)(&sV[(kc * 128 + q * 16 + c) * 8]);
            const bf16x8 b1 = *(const bf16x8*)(&sV[(kc * 128 + 64 + q * 16 + c) * 8]);
            accx0 = __builtin_amdgcn_mfma_f32_16x16x32_bf16(e, b0, accx0, 0, 0, 0);
            accx1 = __builtin_amdgcn_mfma_f32_16x16x32_bf16(e, b1, accx1, 0, 0, 0);
        }

        const unsigned tgt = (unsigned)s;
        for (;;) {
            const unsigned a0 = __hip_atomic_load(flags + fbase + lane,       __ATOMIC_RELAXED, __HIP_MEMORY_SCOPE_AGENT);
            const unsigned a1 = __hip_atomic_load(flags + fbase + 64  + lane, __ATOMIC_RELAXED, __HIP_MEMORY_SCOPE_AGENT);
            const unsigned a2 = __hip_atomic_load(flags + fbase + 128 + lane, __ATOMIC_RELAXED, __HIP_MEMORY_SCOPE_AGENT);
            const unsigned a3 = __hip_atomic_load(flags + fbase + 192 + lane, __ATOMIC_RELAXED, __HIP_MEMORY_SCOPE_AGENT);
            if (__all(a0 >= tgt && a1 >= tgt && a2 >= tgt && a3 >= tgt)) break;
            __builtin_amdgcn_s_sleep(1);
        }
        __asm__ volatile("" ::: "memory");

        const bf16* hb = hbuf + (size_t)(dir * 2 + (s & 1)) * (64 * 512);
        bf16*       hw = hbuf + (size_t)(dir * 2 + ((s + 1) & 1)) * (64 * 512);

        const unsigned long long ha =
            (unsigned long long)hb + (unsigned)(hrow * 1024 + q * 16);
        uint4 af[16];
        asm volatile(
            "global_load_dwordx4 %0,  %16, off sc1\n\t"
            "global_load_dwordx4 %1,  %16, off offset:64   sc1\n\t"
            "global_load_dwordx4 %2,  %16, off offset:128  sc1\n\t"
            "global_load_dwordx4 %3,  %16, off offset:192  sc1\n\t"
            "global_load_dwordx4 %4,  %16, off offset:256  sc1\n\t"
            "global_load_dwordx4 %5,  %16, off offset:320  sc1\n\t"
            "global_load_dwordx4 %6,  %16, off offset:384  sc1\n\t"
            "global_load_dwordx4 %7,  %16, off offset:448  sc1\n\t"
            "global_load_dwordx4 %8,  %16, off offset:512  sc1\n\t"
            "global_load_dwordx4 %9,  %16, off offset:576  sc1\n\t"
            "global_load_dwordx4 %10, %16, off offset:640  sc1\n\t"
            "global_load_dwordx4 %11, %16, off offset:704  sc1\n\t"
            "global_load_dwordx4 %12, %16, off offset:768  sc1\n\t"
            "global_load_dwordx4 %13, %16, off offset:832  sc1\n\t"
            "global_load_dwordx4 %14, %16, off offset:896  sc1\n\t"
            "global_load_dwordx4 %15, %16, off offset:960  sc1\n\t"
            "s_waitcnt vmcnt(0)"
            : "=&v"(af[0]),  "=&v"(af[1]),  "=&v"(af[2]),  "=&v"(af[3]),
              "=&v"(af[4]),  "=&v"(af[5]),  "=&v"(af[6]),  "=&v"(af[7]),
              "=&v"(af[8]),  "=&v"(af[9]),  "=&v"(af[10]), "=&v"(af[11]),
              "=&v"(af[12]), "=&v"(af[13]), "=&v"(af[14]), "=&v"(af[15])
            : "v"(ha)
            : "memory");

        f32x4 acc0 = zz, acc1 = zz;
#pragma unroll
        for (int kc = 0; kc < 16; ++kc) {
            const bf16x8 a  = __builtin_bit_cast(bf16x8, af[kc]);
            const bf16x8 b0 = *(const bf16x8*)(&sW[(kc * 128 + q * 16 + c) * 8]);
            const bf16x8 b1 = *(const bf16x8*)(&sW[(kc * 128 + 64 + q * 16 + c) * 8]);
            acc0 = __builtin_amdgcn_mfma_f32_16x16x32_bf16(a, b0, acc0, 0, 0, 0);
            acc1 = __builtin_amdgcn_mfma_f32_16x16x32_bf16(a, b1, acc1, 0, 0, 0);
        }

        unsigned* hw32 = (unsigned*)hw;
        float hreg[4][2];
#pragma unroll
        for (int r = 0; r < 4; ++r) {
            const int b_ = 16 * wave + 4 * q + r;
            const float m = (&mv.x)[r];
            float hv01[2];
#pragma unroll
            for (int t4 = 0; t4 < 2; ++t4) {
                float v = (t4 ? acc1[r] : acc0[r]) + (t4 ? accx1[r] : accx0[r]) + bias_v[t4];
                const float v1 = __shfl_xor(v, 1);
                const float v2 = __shfl_xor(v, 2);
                const float v3 = __shfl_xor(v, 3);
                const float gi = (g == 0) ? v  : (g == 1) ? v1 : (g == 2) ? v2 : v3;
                const float gf = (g == 0) ? v1 : (g == 1) ? v  : (g == 2) ? v3 : v2;
                const float gG = (g == 0) ? v2 : (g == 1) ? v3 : (g == 2) ? v  : v1;
                const float go = (g == 0) ? v3 : (g == 1) ? v2 : (g == 2) ? v1 : v;
                const float cn = sigmoidf_(gf) * cst[t4][r] + sigmoidf_(gi) * tanhf_(gG);
                float hv       = sigmoidf_(go) * tanhf_(cn);
                cst[t4][r] = cn * m;
                hv *= m;
                hv01[t4] = hv;
            }
            hreg[r][0] = hv01[0]; hreg[r][1] = hv01[1];
            if (g == 0) {
                const unsigned u =
                    (unsigned)__builtin_bit_cast(unsigned short, (bf16)hv01[0]) |
                    ((unsigned)__builtin_bit_cast(unsigned short, (bf16)hv01[1]) << 16);
                __hip_atomic_store(hw32 + b_ * 256 + kb * 4 + (c >> 2), u,
                                   __ATOMIC_RELAXED, __HIP_MEMORY_SCOPE_AGENT);
            }
        }

        __asm__ volatile("" ::: "memory");
        __builtin_amdgcn_s_waitcnt(0x0F70);
        if (lane == 0)
            __hip_atomic_store(flags + myflag, (unsigned)(s + 1),
                               __ATOMIC_RELAXED, __HIP_MEMORY_SCOPE_AGENT);

        if (g == 0) {
            const int j2 = dir * 512 + kb * 8 + 2 * (c >> 2);
#pragma unroll
            for (int r = 0; r < 4; ++r) {
                const int b_ = 16 * wave + 4 * q + r;
                float2 o2; o2.x = hreg[r][0]; o2.y = hreg[r][1];
                *(float2*)(&out[(size_t)(tt * 64 + b_) * 1024 + j2]) = o2;
            }
        }
        if (s < 127) {
            const int tt_n = dir ? (126 - s) : (s + 1);
            const float* erow = (qv_n >= 0) ? (table + (size_t)qv_n * 512) : zrow;
#pragma unroll
            for (int kc = 0; kc < 16; ++kc) {
                xe[2 * kc]     = *(const uint4*)(erow + kc * 32 + q * 8);
                xe[2 * kc + 1] = *(const uint4*)(erow + kc * 32 + q * 8 + 4);
            }
            mv = *(const float4*)(&mask[tt_n * 64 + 16 * wave + 4 * q]);
            if (s < 126) {
                const int tt_n2 = dir ? (125 - s) : (s + 2);
                qv_n = data[tt_n2 * 64 + hrow];
            }
        }
    }
}

extern "C" void kernel_launch(void* const* d_in, const int* in_sizes, int n_in,
                              void* d_out, int out_size, void* d_ws, size_t ws_size,
                              hipStream_t stream) {
    const int*   data  = (const int*)d_in[0];
    const float* mask  = (const float*)d_in[1];
    const float* table = (const float*)d_in[2];
    const float* wih_f = (const float*)d_in[3];
    const float* whh_f = (const float*)d_in[4];
    const float* bih_f = (const float*)d_in[5];
    const float* bhh_f = (const float*)d_in[6];
    const float* wih_b = (const float*)d_in[7];
    const float* whh_b = (const float*)d_in[8];
    const float* bih_b = (const float*)d_in[9];
    const float* bhh_b = (const float*)d_in[10];
    float* outp = (float*)d_out;

    char* ws = (char*)d_ws;
    bf16*     hbuf  = (bf16*)(ws + HB_OFF);
    unsigned* flagp = (unsigned*)(ws + FLAG_OFF);

    if (ws_size >= WS_NEED) {
        bf16*  ebf = (bf16*)(ws + EBF_OFF);
        float* xp  = (float*)(ws + XP_OFF);
        unsigned short* xf = (unsigned short*)(ws + XF_OFF);
        emb_gather<<<2048, 256, 0, stream>>>(data, table, ebf,
                                             (unsigned long long*)ws);
        fused_scan<<<1152, 256, 0, stream>>>(mask, whh_f, whh_b,
                                             bih_f, bhh_f, bih_b, bhh_b,
                                             wih_f, wih_b, ebf, xp,
                                             hbuf, flagp, xf, outp);
    } else {
        const float* zrow = (const float*)(ws + XF_OFF);   // legacy zrow bytes
        init_ws_legacy<<<(int)((WS_ZERO_BYTES / 8 + 255) / 256), 256, 0, stream>>>(
            (unsigned long long*)ws);
        lstm_scan_legacy<<<128, 256, 0, stream>>>(data, mask, table,
                                                  wih_f, whh_f, bih_f, bhh_f,
                                                  wih_b, whh_b, bih_b, bhh_b,
                                                  hbuf, flagp, zrow, outp);
    }
}

// Round 9
// 1014.024 us; speedup vs baseline: 1.2501x; 1.2501x over previous
//
#include <hip/hip_runtime.h>

// NLReader bidirectional LSTM, MI355X — persistent scan, fence-free MALL relay.
//
// Round-17 = VERBATIM round-13 (session best: 930 us fused, 1017 us total).
// Round-13 is bracketed as a local optimum by five failed perturbations:
//   r11 XCD-local sc0 relay        +650 us (single-L2 flag hotspot)
//   r14 16-unit blocks             +210 us (doubled serial epilogue)
//   r15b tight poll + head-xq      +87  us (zero-head-start latency exposed)
//   r16 issue-only prefetch+fence  +260 us (sched_barrier kills scheduling)
// Steady state = serial MALL RT chain (store-ack -> flag -> poll -> h-fetch),
// ~7.3 us/step; counters show all pipes idle (latency-bound, not throughput).
//
//  * Grid 1152: bid<128 = scan role; bid>=128 = xproj role (dir x cc x sh).
//  * xproj stores xp with sc1 (MALL write-through), vmcnt(0) ack, u16 group
//    flag; scan gates on the group flag at prologue + every 8th step.
//  * scan: 8 units/block, wave-matched relay flags (1 load/lane), sc1 MALL
//    h relay, one-asm-node h-fetch (16x dwordx4 + vmcnt(0)), f32 c-state in
//    registers, fa/fb pipelined poll, xq loaded in tail with vmcnt(0).
//  * emb_gather prepass also zeroes the 266 KB scan region.
//
// Block (dir=bid>>6, kb=bid&63) owns 8 hidden units as 32 permuted gate cols:
//   tile t4 in {0,1}, lane col c in [0,16): gate g = c&3, unit jj = 2*(c>>2)+t4
//   orig Wih/Whh row = g*512 + kb*8 + jj.

typedef float  f32x4  __attribute__((ext_vector_type(4)));
typedef __bf16 bf16x8 __attribute__((ext_vector_type(8)));
typedef __bf16 bf16;

#define HB_OFF   ((size_t)0)        // 4 x [64 x 512] bf16 = 262144 B
#define FLAG_OFF ((size_t)262144)   // 512 x u32 = 2048 B
#define XF_OFF   ((size_t)264192)   // 1024 x u16 xproj group flags (new path)
                                    // (same bytes are ZROW in the legacy path)
#define WS_ZERO_BYTES ((size_t)266240)
#define XP_OFF   ((size_t)266240)                 // 128 blk*128 s*2048 f32
#define XP_BYTES ((size_t)134217728)
#define EBF_OFF  (XP_OFF + XP_BYTES)              // 8192 rows * 512 bf16
#define EBF_BYTES ((size_t)8388608)
#define WS_NEED  (EBF_OFF + EBF_BYTES)            // 142,872,576 B (unchanged)

__device__ __forceinline__ float sigmoidf_(float x) {
    return 1.0f / (1.0f + __expf(-x));
}
__device__ __forceinline__ float tanhf_(float x) {
    return 2.0f * sigmoidf_(2.0f * x) - 1.0f;
}
__device__ __forceinline__ bf16x8 cvt8(const float* p) {
    float4 a = *(const float4*)p;
    float4 b = *(const float4*)(p + 4);
    bf16x8 r;
    r[0] = (bf16)a.x; r[1] = (bf16)a.y; r[2] = (bf16)a.z; r[3] = (bf16)a.w;
    r[4] = (bf16)b.x; r[5] = (bf16)b.y; r[6] = (bf16)b.z; r[7] = (bf16)b.w;
    return r;
}
__device__ __forceinline__ bf16x8 cvt8v(uint4 u0, uint4 u1) {
    float4 a = __builtin_bit_cast(float4, u0);
    float4 b = __builtin_bit_cast(float4, u1);
    bf16x8 r;
    r[0] = (bf16)a.x; r[1] = (bf16)a.y; r[2] = (bf16)a.z; r[3] = (bf16)a.w;
    r[4] = (bf16)b.x; r[5] = (bf16)b.y; r[6] = (bf16)b.z; r[7] = (bf16)b.w;
    return r;
}
__device__ __forceinline__ void store4_sc1(float* p, f32x4 v) {
    asm volatile("global_store_dwordx4 %0, %1, off sc1"
                 :: "v"((unsigned long long)p), "v"(v) : "memory");
}
__device__ __forceinline__ void wait_xf(unsigned long long a) {
    for (;;) {
        unsigned v;
        asm volatile("global_load_ushort %0, %1, off sc1\n\t"
                     "s_waitcnt vmcnt(0)"
                     : "=&v"(v) : "v"(a) : "memory");
        if (v != 0) break;
        __builtin_amdgcn_s_sleep(2);
    }
}

__global__ __launch_bounds__(256) void init_ws_legacy(unsigned long long* __restrict__ w) {
    const size_t i = (size_t)blockIdx.x * 256 + threadIdx.x;
    if (i < WS_ZERO_BYTES / 8) w[i] = 0ull;
}

// ---- pre-pass: gather + f32->bf16 embedding rows; pad rows zeroed.
// Blocks 0..129 also zero the 266 KB scan region (hbuf + relay flags + XF).
__global__ __launch_bounds__(256) void emb_gather(
    const int* __restrict__ data, const float* __restrict__ table,
    bf16* __restrict__ ebf, unsigned long long* __restrict__ wz)
{
    const int bid = blockIdx.x, tid = threadIdx.x;
    if (bid < 130) {                                // 130*256*8 = 266240 B
        wz[(size_t)bid * 256 + tid] = 0ull;
    }
    const int wave = tid >> 6, lane = tid & 63;
    const int rr = bid * 4 + wave;                  // 0..8191 = t*64+b
    const int qv = data[rr];
    bf16x8 v;
    if (qv >= 0) {
        v = cvt8(table + (size_t)qv * 512 + lane * 8);
    } else {
#pragma unroll
        for (int i = 0; i < 8; ++i) v[i] = (bf16)0.f;
    }
    *(bf16x8*)(ebf + (size_t)rr * 512 + lane * 8) = v;
}

// ---- fused kernel: scan role (bid<128) + xproj role (bid>=128) ----
__global__ __launch_bounds__(256, 1) void fused_scan(
    const float* __restrict__ mask,
    const float* __restrict__ whh_f, const float* __restrict__ whh_b,
    const float* __restrict__ bih_f, const float* __restrict__ bhh_f,
    const float* __restrict__ bih_b, const float* __restrict__ bhh_b,
    const float* __restrict__ wih_f, const float* __restrict__ wih_b,
    const bf16* __restrict__ ebf,
    float* __restrict__ xp,
    bf16* __restrict__ hbuf,
    unsigned* __restrict__ flags,
    unsigned short* __restrict__ xf,
    float* __restrict__ out)
{
    __shared__ bf16 sM[4096 * 8];      // 64 KB; scan role uses first 32 KB

    const int tid = threadIdx.x, bid = blockIdx.x;
    const int wave = tid >> 6, lane = tid & 63;
    const int c = lane & 15, q = lane >> 4;

    if (bid >= 128) {
        // ================= xproj role =================
        // xbid = dir*512 + cc*16 + sh; computes xp for kb=2cc,2cc+1, steps
        // sh*8..sh*8+7, in the scan's exact per-lane layout (kc-ascending
        // MFMA order -> bitwise-identical numerics).
        const int xbid = bid - 128;
        const int dir = xbid >> 9, cc = (xbid >> 4) & 31, sh = xbid & 15;
        const float* wih = dir ? wih_b : wih_f;

        for (int e = tid; e < 4096; e += 256) {
            const int ec = e & 15, eq = (e >> 4) & 3, et = (e >> 6) & 3, ekc = e >> 8;
            const int kbx = 2 * cc + (et >> 1), t4x = et & 1;
            const size_t orig = (size_t)((ec & 3) * 512 + kbx * 8 + 2 * (ec >> 2) + t4x);
            *(bf16x8*)(&sM[e * 8]) = cvt8(&wih[orig * 512 + ekc * 32 + eq * 8]);
        }
        __syncthreads();

        const int hrow = 16 * wave + c;
        const f32x4 zz = {0.f, 0.f, 0.f, 0.f};
        const size_t flin = (size_t)wave * 512 + (q * 16 + c) * 8;

        for (int s0 = 0; s0 < 8; ++s0) {
            const int s = sh * 8 + s0;
            const int tt = dir ? (127 - s) : s;
            const bf16* arow = ebf + (size_t)(tt * 64 + hrow) * 512;
            uint4 af[16];
#pragma unroll
            for (int kc = 0; kc < 16; ++kc)
                af[kc] = *(const uint4*)(arow + kc * 32 + q * 8);

            f32x4 acc0 = zz, acc1 = zz, acc2 = zz, acc3 = zz;
#pragma unroll
            for (int kc = 0; kc < 16; ++kc) {
                const bf16x8 a = __builtin_bit_cast(bf16x8, af[kc]);
                acc0 = __builtin_amdgcn_mfma_f32_16x16x32_bf16(
                    a, *(const bf16x8*)(&sM[(kc * 256 +   0 + q * 16 + c) * 8]), acc0, 0, 0, 0);
                acc1 = __builtin_amdgcn_mfma_f32_16x16x32_bf16(
                    a, *(const bf16x8*)(&sM[(kc * 256 +  64 + q * 16 + c) * 8]), acc1, 0, 0, 0);
                acc2 = __builtin_amdgcn_mfma_f32_16x16x32_bf16(
                    a, *(const bf16x8*)(&sM[(kc * 256 + 128 + q * 16 + c) * 8]), acc2, 0, 0, 0);
                acc3 = __builtin_amdgcn_mfma_f32_16x16x32_bf16(
                    a, *(const bf16x8*)(&sM[(kc * 256 + 192 + q * 16 + c) * 8]), acc3, 0, 0, 0);
            }
            const size_t r0 = ((size_t)(dir * 64 + 2 * cc)     * 128 + s) * 2048 + flin;
            const size_t r1 = ((size_t)(dir * 64 + 2 * cc + 1) * 128 + s) * 2048 + flin;
            store4_sc1(&xp[r0],     acc0);      // kb=2cc,  t4=0
            store4_sc1(&xp[r0 + 4], acc1);      // kb=2cc,  t4=1
            store4_sc1(&xp[r1],     acc2);      // kb=2cc+1,t4=0
            store4_sc1(&xp[r1 + 4], acc3);      // kb=2cc+1,t4=1
        }
        __builtin_amdgcn_s_waitcnt(0x0F70);     // this wave's sc1 stores acked
        __syncthreads();                        // all 4 waves acked
        if (tid == 0) {
            const unsigned long long fa =
                (unsigned long long)&xf[(dir * 32 + cc) * 16 + sh];
            asm volatile("global_store_short %0, %1, off sc1"
                         :: "v"(fa), "v"(1u) : "memory");
        }
        return;
    }

    // ================= scan role (verbatim round-10/12 + XF gating) =========
    const int dir = bid >> 6, kb = bid & 63;
    const int g = c & 3;

    const float* whh = dir ? whh_b : whh_f;
    const float* bih = dir ? bih_b : bih_f;
    const float* bhh = dir ? bhh_b : bhh_f;

    for (int e = tid; e < 2048; e += 256) {
        const int ec = e & 15, eq = (e >> 4) & 3, et = (e >> 6) & 1, ekc = e >> 7;
        const size_t orig = (size_t)((ec & 3) * 512 + kb * 8 + 2 * (ec >> 2) + et);
        *(bf16x8*)(&sM[e * 8]) = cvt8(&whh[orig * 512 + ekc * 32 + eq * 8]);
    }
    float bias_v[2];
#pragma unroll
    for (int t4 = 0; t4 < 2; ++t4) {
        const int orig = g * 512 + kb * 8 + 2 * (c >> 2) + t4;
        bias_v[t4] = bih[orig] + bhh[orig];
    }

    float cst[2][4] = {{0.f, 0.f, 0.f, 0.f}, {0.f, 0.f, 0.f, 0.f}};
    const int hrow = 16 * wave + c;
    const int myflag = dir * 256 + wave * 64 + kb;
    const int fidx   = dir * 256 + wave * 64 + lane;
    const f32x4 zz = {0.f, 0.f, 0.f, 0.f};
    __syncthreads();                    // sM(=sW) ready; no syncs after this

    // xproj group-flag base for this block's (dir, cc=kb>>1)
    const unsigned long long xfb =
        (unsigned long long)(xf + ((size_t)(dir * 32 + (kb >> 1)) * 16));

    // prologue: wait group 0, then x-gate fragment + mask for step 0
    const float* xpb = xp + (size_t)bid * 128 * 2048
                          + (size_t)wave * 512 + (q * 16 + c) * 8;
    wait_xf(xfb);
    float4 xq0, xq1;
    {
        uint4 u0, u1;
        const unsigned long long xa = (unsigned long long)xpb;
        asm volatile("global_load_dwordx4 %0, %2, off sc1\n\t"
                     "global_load_dwordx4 %1, %2, off offset:16 sc1\n\t"
                     "s_waitcnt vmcnt(0)"
                     : "=&v"(u0), "=&v"(u1) : "v"(xa) : "memory");
        xq0 = __builtin_bit_cast(float4, u0);
        xq1 = __builtin_bit_cast(float4, u1);
    }
    float4 mv;
    {
        const int tt0 = dir ? 127 : 0;
        mv = *(const float4*)(&mask[tt0 * 64 + 16 * wave + 4 * q]);
    }

    for (int s = 0; s < 128; ++s) {
        const int tt = dir ? (127 - s) : s;

        // ---- wait: the 64 wave-matched producer waves completed step s-1 ----
        const unsigned tgt = (unsigned)s;
        unsigned fa = __hip_atomic_load(flags + fidx, __ATOMIC_RELAXED, __HIP_MEMORY_SCOPE_AGENT);
        unsigned fb = __hip_atomic_load(flags + fidx, __ATOMIC_RELAXED, __HIP_MEMORY_SCOPE_AGENT);
        for (;;) {
            if (__all(fa >= tgt)) break;
            fa = fb;
            fb = __hip_atomic_load(flags + fidx, __ATOMIC_RELAXED, __HIP_MEMORY_SCOPE_AGENT);
        }
        __asm__ volatile("" ::: "memory");   // keep h-loads below the poll

        const bf16* hb = hbuf + (size_t)(dir * 2 + (s & 1)) * (64 * 512);
        bf16*       hw = hbuf + (size_t)(dir * 2 + ((s + 1) & 1)) * (64 * 512);

        // ---- h A-fragments: ONE asm node = 16 sc1 dwordx4 + vmcnt(0) ----
        const unsigned long long ha =
            (unsigned long long)hb + (unsigned)(hrow * 1024 + q * 16);
        uint4 af[16];
        asm volatile(
            "global_load_dwordx4 %0,  %16, off sc1\n\t"
            "global_load_dwordx4 %1,  %16, off offset:64   sc1\n\t"
            "global_load_dwordx4 %2,  %16, off offset:128  sc1\n\t"
            "global_load_dwordx4 %3,  %16, off offset:192  sc1\n\t"
            "global_load_dwordx4 %4,  %16, off offset:256  sc1\n\t"
            "global_load_dwordx4 %5,  %16, off offset:320  sc1\n\t"
            "global_load_dwordx4 %6,  %16, off offset:384  sc1\n\t"
            "global_load_dwordx4 %7,  %16, off offset:448  sc1\n\t"
            "global_load_dwordx4 %8,  %16, off offset:512  sc1\n\t"
            "global_load_dwordx4 %9,  %16, off offset:576  sc1\n\t"
            "global_load_dwordx4 %10, %16, off offset:640  sc1\n\t"
            "global_load_dwordx4 %11, %16, off offset:704  sc1\n\t"
            "global_load_dwordx4 %12, %16, off offset:768  sc1\n\t"
            "global_load_dwordx4 %13, %16, off offset:832  sc1\n\t"
            "global_load_dwordx4 %14, %16, off offset:896  sc1\n\t"
            "global_load_dwordx4 %15, %16, off offset:960  sc1\n\t"
            "s_waitcnt vmcnt(0)"
            : "=&v"(af[0]),  "=&v"(af[1]),  "=&v"(af[2]),  "=&v"(af[3]),
              "=&v"(af[4]),  "=&v"(af[5]),  "=&v"(af[6]),  "=&v"(af[7]),
              "=&v"(af[8]),  "=&v"(af[9]),  "=&v"(af[10]), "=&v"(af[11]),
              "=&v"(af[12]), "=&v"(af[13]), "=&v"(af[14]), "=&v"(af[15])
            : "v"(ha)
            : "memory");

        f32x4 acc0 = zz, acc1 = zz;
#pragma unroll
        for (int kc = 0; kc < 16; ++kc) {
            const bf16x8 a  = __builtin_bit_cast(bf16x8, af[kc]);
            const bf16x8 b0 = *(const bf16x8*)(&sM[(kc * 128 + q * 16 + c) * 8]);
            const bf16x8 b1 = *(const bf16x8*)(&sM[(kc * 128 + 64 + q * 16 + c) * 8]);
            acc0 = __builtin_amdgcn_mfma_f32_16x16x32_bf16(a, b0, acc0, 0, 0, 0);
            acc1 = __builtin_amdgcn_mfma_f32_16x16x32_bf16(a, b1, acc1, 0, 0, 0);
        }

        // ---- epilogue: C/D layout col=lane&15, row=q*4+r ----
        unsigned* hw32 = (unsigned*)hw;
        float hreg[4][2];
#pragma unroll
        for (int r = 0; r < 4; ++r) {
            const int b_ = 16 * wave + 4 * q + r;
            const float m = (&mv.x)[r];
            float hv01[2];
#pragma unroll
            for (int t4 = 0; t4 < 2; ++t4) {
                float v = (t4 ? acc1[r] : acc0[r])
                        + (t4 ? (&xq1.x)[r] : (&xq0.x)[r]) + bias_v[t4];
                const float v1 = __shfl_xor(v, 1);
                const float v2 = __shfl_xor(v, 2);
                const float v3 = __shfl_xor(v, 3);
                const float gi = (g == 0) ? v  : (g == 1) ? v1 : (g == 2) ? v2 : v3;
                const float gf = (g == 0) ? v1 : (g == 1) ? v  : (g == 2) ? v3 : v2;
                const float gG = (g == 0) ? v2 : (g == 1) ? v3 : (g == 2) ? v  : v1;
                const float go = (g == 0) ? v3 : (g == 1) ? v2 : (g == 2) ? v1 : v;
                const float cn = sigmoidf_(gf) * cst[t4][r] + sigmoidf_(gi) * tanhf_(gG);
                float hv       = sigmoidf_(go) * tanhf_(cn);
                cst[t4][r] = cn * m;
                hv *= m;
                hv01[t4] = hv;
            }
            hreg[r][0] = hv01[0]; hreg[r][1] = hv01[1];
            if (g == 0) {                   // packed 2xbf16 -> one u32 sc1 store
                const unsigned u =
                    (unsigned)__builtin_bit_cast(unsigned short, (bf16)hv01[0]) |
                    ((unsigned)__builtin_bit_cast(unsigned short, (bf16)hv01[1]) << 16);
                __hip_atomic_store(hw32 + b_ * 256 + kb * 4 + (c >> 2), u,
                                   __ATOMIC_RELAXED, __HIP_MEMORY_SCOPE_AGENT);
            }
        }

        // release: all h sc1-stores acked at MALL before flag store
        __asm__ volatile("" ::: "memory");
        __builtin_amdgcn_s_waitcnt(0x0F70);  // vmcnt(0)
        if (lane == 0)
            __hip_atomic_store(flags + myflag, (unsigned)(s + 1),
                               __ATOMIC_RELAXED, __HIP_MEMORY_SCOPE_AGENT);

        // ---- step tail (hidden behind other blocks' consumption) ----
        if (g == 0) {
            const int j2 = dir * 512 + kb * 8 + 2 * (c >> 2);
#pragma unroll
            for (int r = 0; r < 4; ++r) {
                const int b_ = 16 * wave + 4 * q + r;
                float2 o2; o2.x = hreg[r][0]; o2.y = hreg[r][1];
                *(float2*)(&out[(size_t)(tt * 64 + b_) * 1024 + j2]) = o2;
            }
        }
        if (s < 127) {
            if (((s + 1) & 7) == 0)                 // new 8-step group
                wait_xf(xfb + (unsigned)(((s + 1) >> 3) * 2));
            uint4 u0, u1;
            const unsigned long long xa =
                (unsigned long long)(xpb + (size_t)(s + 1) * 2048);
            asm volatile("global_load_dwordx4 %0, %2, off sc1\n\t"
                         "global_load_dwordx4 %1, %2, off offset:16 sc1\n\t"
                         "s_waitcnt vmcnt(0)"
                         : "=&v"(u0), "=&v"(u1) : "v"(xa) : "memory");
            xq0 = __builtin_bit_cast(float4, u0);
            xq1 = __builtin_bit_cast(float4, u1);
            const int tt_n = dir ? (126 - s) : (s + 1);
            mv  = *(const float4*)(&mask[tt_n * 64 + 16 * wave + 4 * q]);
        }
    }
}

// ================= verbatim round-9 fallback (ws too small) =================
__global__ __launch_bounds__(256, 1) void lstm_scan_legacy(
    const int*   __restrict__ data,
    const float* __restrict__ mask,
    const float* __restrict__ table,
    const float* __restrict__ wih_f, const float* __restrict__ whh_f,
    const float* __restrict__ bih_f, const float* __restrict__ bhh_f,
    const float* __restrict__ wih_b, const float* __restrict__ whh_b,
    const float* __restrict__ bih_b, const float* __restrict__ bhh_b,
    bf16* __restrict__ hbuf,
    unsigned* __restrict__ flags,
    const float* __restrict__ zrow,
    float* __restrict__ out)
{
    __shared__ bf16 sW[2048 * 8];
    __shared__ bf16 sV[2048 * 8];

    const int tid = threadIdx.x, bid = blockIdx.x;
    const int dir = bid >> 6, kb = bid & 63;
    const int wave = tid >> 6, lane = tid & 63;
    const int c = lane & 15, q = lane >> 4, g = c & 3;

    const float* wih = dir ? wih_b : wih_f;
    const float* whh = dir ? whh_b : whh_f;
    const float* bih = dir ? bih_b : bih_f;
    const float* bhh = dir ? bhh_b : bhh_f;

    for (int e = tid; e < 2048; e += 256) {
        const int ec = e & 15, eq = (e >> 4) & 3, et = (e >> 6) & 1, ekc = e >> 7;
        const size_t orig = (size_t)((ec & 3) * 512 + kb * 8 + 2 * (ec >> 2) + et);
        const size_t off = orig * 512 + ekc * 32 + eq * 8;
        *(bf16x8*)(&sW[e * 8]) = cvt8(&whh[off]);
        *(bf16x8*)(&sV[e * 8]) = cvt8(&wih[off]);
    }
    float bias_v[2];
#pragma unroll
    for (int t4 = 0; t4 < 2; ++t4) {
        const int orig = g * 512 + kb * 8 + 2 * (c >> 2) + t4;
        bias_v[t4] = bih[orig] + bhh[orig];
    }

    float cst[2][4] = {{0.f, 0.f, 0.f, 0.f}, {0.f, 0.f, 0.f, 0.f}};
    const int hrow = 16 * wave + c;
    const int myflag = dir * 256 + kb * 4 + wave;
    const int fbase = dir * 256;
    const f32x4 zz = {0.f, 0.f, 0.f, 0.f};
    __syncthreads();

    uint4 xe[32];
    float4 mv;
    int qv_n;
    {
        const int tt0 = dir ? 127 : 0;
        const int qv0 = data[tt0 * 64 + hrow];
        mv = *(const float4*)(&mask[tt0 * 64 + 16 * wave + 4 * q]);
        const float* erow = (qv0 >= 0) ? (table + (size_t)qv0 * 512) : zrow;
#pragma unroll
        for (int kc = 0; kc < 16; ++kc) {
            xe[2 * kc]     = *(const uint4*)(erow + kc * 32 + q * 8);
            xe[2 * kc + 1] = *(const uint4*)(erow + kc * 32 + q * 8 + 4);
        }
        const int tt1 = dir ? 126 : 1;
        qv_n = data[tt1 * 64 + hrow];
    }

    for (int s = 0; s < 128; ++s) {
        const int tt = dir ? (127 - s) : s;

        f32x4 accx0 = zz, accx1 = zz;
#pragma unroll
        for (int kc = 0; kc < 16; ++kc) {
            const bf16x8 e  = cvt8v(xe[2 * kc], xe[2 * kc + 1]);
            const bf16x8 b0 = *(const bf16x8*)(&sV[(kc * 128 + q * 16 + c) * 8]);
            const bf16x8 b1 = *(const bf16x8*)(&sV[(kc * 128 + 64 + q * 16 + c) * 8]);
            accx0 = __builtin_amdgcn_mfma_f32_16x16x32_bf16(e, b0, accx0, 0, 0, 0);
            accx1 = __builtin_amdgcn_mfma_f32_16x16x32_bf16(e, b1, accx1, 0, 0, 0);
        }

        const unsigned tgt = (unsigned)s;
        for (;;) {
            const unsigned a0 = __hip_atomic_load(flags + fbase + lane,       __ATOMIC_RELAXED, __HIP_MEMORY_SCOPE_AGENT);
            const unsigned a1 = __hip_atomic_load(flags + fbase + 64  + lane, __ATOMIC_RELAXED, __HIP_MEMORY_SCOPE_AGENT);
            const unsigned a2 = __hip_atomic_load(flags + fbase + 128 + lane, __ATOMIC_RELAXED, __HIP_MEMORY_SCOPE_AGENT);
            const unsigned a3 = __hip_atomic_load(flags + fbase + 192 + lane, __ATOMIC_RELAXED, __HIP_MEMORY_SCOPE_AGENT);
            if (__all(a0 >= tgt && a1 >= tgt && a2 >= tgt && a3 >= tgt)) break;
            __builtin_amdgcn_s_sleep(1);
        }
        __asm__ volatile("" ::: "memory");

        const bf16* hb = hbuf + (size_t)(dir * 2 + (s & 1)) * (64 * 512);
        bf16*       hw = hbuf + (size_t)(dir * 2 + ((s + 1) & 1)) * (64 * 512);

        const unsigned long long ha =
            (unsigned long long)hb + (unsigned)(hrow * 1024 + q * 16);
        uint4 af[16];
        asm volatile(
            "global_load_dwordx4 %0,  %16, off sc1\n\t"
            "global_load_dwordx4 %1,  %16, off offset:64   sc1\n\t"
            "global_load_dwordx4 %2,  %16, off offset:128  sc1\n\t"
            "global_load_dwordx4 %3,  %16, off offset:192  sc1\n\t"
            "global_load_dwordx4 %4,  %16, off offset:256  sc1\n\t"
            "global_load_dwordx4 %5,  %16, off offset:320  sc1\n\t"
            "global_load_dwordx4 %6,  %16, off offset:384  sc1\n\t"
            "global_load_dwordx4 %7,  %16, off offset:448  sc1\n\t"
            "global_load_dwordx4 %8,  %16, off offset:512  sc1\n\t"
            "global_load_dwordx4 %9,  %16, off offset:576  sc1\n\t"
            "global_load_dwordx4 %10, %16, off offset:640  sc1\n\t"
            "global_load_dwordx4 %11, %16, off offset:704  sc1\n\t"
            "global_load_dwordx4 %12, %16, off offset:768  sc1\n\t"
            "global_load_dwordx4 %13, %16, off offset:832  sc1\n\t"
            "global_load_dwordx4 %14, %16, off offset:896  sc1\n\t"
            "global_load_dwordx4 %15, %16, off offset:960  sc1\n\t"
            "s_waitcnt vmcnt(0)"
            : "=&v"(af[0]),  "=&v"(af[1]),  "=&v"(af[2]),  "=&v"(af[3]),
              "=&v"(af[4]),  "=&v"(af[5]),  "=&v"(af[6]),  "=&v"(af[7]),
              "=&v"(af[8]),  "=&v"(af[9]),  "=&v"(af[10]), "=&v"(af[11]),
              "=&v"(af[12]), "=&v"(af[13]), "=&v"(af[14]), "=&v"(af[15])
            : "v"(ha)
            : "memory");

        f32x4 acc0 = zz, acc1 = zz;
#pragma unroll
        for (int kc = 0; kc < 16; ++kc) {
            const bf16x8 a  = __builtin_bit_cast(bf16x8, af[kc]);
            const bf16x8 b0 = *(const bf16x8*)(&sW[(kc * 128 + q * 16 + c) * 8]);
            const bf16x8 b1 = *(const bf16x8*)(&sW[(kc * 128 + 64 + q * 16 + c) * 8]);
            acc0 = __builtin_amdgcn_mfma_f32_16x16x32_bf16(a, b0, acc0, 0, 0, 0);
            acc1 = __builtin_amdgcn_mfma_f32_16x16x32_bf16(a, b1, acc1, 0, 0, 0);
        }

        unsigned* hw32 = (unsigned*)hw;
        float hreg[4][2];
#pragma unroll
        for (int r = 0; r < 4; ++r) {
            const int b_ = 16 * wave + 4 * q + r;
            const float m = (&mv.x)[r];
            float hv01[2];
#pragma unroll
            for (int t4 = 0; t4 < 2; ++t4) {
                float v = (t4 ? acc1[r] : acc0[r]) + (t4 ? accx1[r] : accx0[r]) + bias_v[t4];
                const float v1 = __shfl_xor(v, 1);
                const float v2 = __shfl_xor(v, 2);
                const float v3 = __shfl_xor(v, 3);
                const float gi = (g == 0) ? v  : (g == 1) ? v1 : (g == 2) ? v2 : v3;
                const float gf = (g == 0) ? v1 : (g == 1) ? v  : (g == 2) ? v3 : v2;
                const float gG = (g == 0) ? v2 : (g == 1) ? v3 : (g == 2) ? v  : v1;
                const float go = (g == 0) ? v3 : (g == 1) ? v2 : (g == 2) ? v1 : v;
                const float cn = sigmoidf_(gf) * cst[t4][r] + sigmoidf_(gi) * tanhf_(gG);
                float hv       = sigmoidf_(go) * tanhf_(cn);
                cst[t4][r] = cn * m;
                hv *= m;
                hv01[t4] = hv;
            }
            hreg[r][0] = hv01[0]; hreg[r][1] = hv01[1];
            if (g == 0) {
                const unsigned u =
                    (unsigned)__builtin_bit_cast(unsigned short, (bf16)hv01[0]) |
                    ((unsigned)__builtin_bit_cast(unsigned short, (bf16)hv01[1]) << 16);
                __hip_atomic_store(hw32 + b_ * 256 + kb * 4 + (c >> 2), u,
                                   __ATOMIC_RELAXED, __HIP_MEMORY_SCOPE_AGENT);
            }
        }

        __asm__ volatile("" ::: "memory");
        __builtin_amdgcn_s_waitcnt(0x0F70);
        if (lane == 0)
            __hip_atomic_store(flags + myflag, (unsigned)(s + 1),
                               __ATOMIC_RELAXED, __HIP_MEMORY_SCOPE_AGENT);

        if (g == 0) {
            const int j2 = dir * 512 + kb * 8 + 2 * (c >> 2);
#pragma unroll
            for (int r = 0; r < 4; ++r) {
                const int b_ = 16 * wave + 4 * q + r;
                float2 o2; o2.x = hreg[r][0]; o2.y = hreg[r][1];
                *(float2*)(&out[(size_t)(tt * 64 + b_) * 1024 + j2]) = o2;
            }
        }
        if (s < 127) {
            const int tt_n = dir ? (126 - s) : (s + 1);
            const float* erow = (qv_n >= 0) ? (table + (size_t)qv_n * 512) : zrow;
#pragma unroll
            for (int kc = 0; kc < 16; ++kc) {
                xe[2 * kc]     = *(const uint4*)(erow + kc * 32 + q * 8);
                xe[2 * kc + 1] = *(const uint4*)(erow + kc * 32 + q * 8 + 4);
            }
            mv = *(const float4*)(&mask[tt_n * 64 + 16 * wave + 4 * q]);
            if (s < 126) {
                const int tt_n2 = dir ? (125 - s) : (s + 2);
                qv_n = data[tt_n2 * 64 + hrow];
            }
        }
    }
}

extern "C" void kernel_launch(void* const* d_in, const int* in_sizes, int n_in,
                              void* d_out, int out_size, void* d_ws, size_t ws_size,
                              hipStream_t stream) {
    const int*   data  = (const int*)d_in[0];
    const float* mask  = (const float*)d_in[1];
    const float* table = (const float*)d_in[2];
    const float* wih_f = (const float*)d_in[3];
    const float* whh_f = (const float*)d_in[4];
    const float* bih_f = (const float*)d_in[5];
    const float* bhh_f = (const float*)d_in[6];
    const float* wih_b = (const float*)d_in[7];
    const float* whh_b = (const float*)d_in[8];
    const float* bih_b = (const float*)d_in[9];
    const float* bhh_b = (const float*)d_in[10];
    float* outp = (float*)d_out;

    char* ws = (char*)d_ws;
    bf16*     hbuf  = (bf16*)(ws + HB_OFF);
    unsigned* flagp = (unsigned*)(ws + FLAG_OFF);

    if (ws_size >= WS_NEED) {
        bf16*  ebf = (bf16*)(ws + EBF_OFF);
        float* xp  = (float*)(ws + XP_OFF);
        unsigned short* xf = (unsigned short*)(ws + XF_OFF);
        emb_gather<<<2048, 256, 0, stream>>>(data, table, ebf,
                                             (unsigned long long*)ws);
        fused_scan<<<1152, 256, 0, stream>>>(mask, whh_f, whh_b,
                                             bih_f, bhh_f, bih_b, bhh_b,
                                             wih_f, wih_b, ebf, xp,
                                             hbuf, flagp, xf, outp);
    } else {
        const float* zrow = (const float*)(ws + XF_OFF);   // legacy zrow bytes
        init_ws_legacy<<<(int)((WS_ZERO_BYTES / 8 + 255) / 256), 256, 0, stream>>>(
            (unsigned long long*)ws);
        lstm_scan_legacy<<<128, 256, 0, stream>>>(data, mask, table,
                                                  wih_f, whh_f, bih_f, bhh_f,
                                                  wih_b, whh_b, bih_b, bhh_b,
                                                  hbuf, flagp, zrow, outp);
    }
}

// Round 10
// 852.103 us; speedup vs baseline: 1.4877x; 1.1900x over previous
//
#include <hip/hip_runtime.h>

// NLReader bidirectional LSTM, MI355X — persistent scan, fence-free MALL relay.
//
// Round-18 = round-13/17 (session best, 1014 us total) + two protocol-neutral
// changes:
//  (a) Epilogue activate-then-shuffle: each lane applies its OWN gate's
//      activation (sigmoid, or tanh via the 2*sig(2x)-1 identity, branchless
//      cndmask -> bitwise identical) BEFORE the quad shuffle. Transcendental
//      evals drop 40 -> 16 per thread per step; this VALU is on the serial
//      relay chain (MFMA -> epilogue -> store-ack -> flag).
//  (b) xproj block order sh-major (xbid = sh*64 + dir*32 + cc): the sh=0
//      group-flag producers for BOTH dirs are in the first resident cohort,
//      trimming the dir-1 scan prologue's startup skew. Pure permutation —
//      identical stores and flag addresses.
// Relay protocol VERBATIM r13 (bracketed by r11/r14/r15b/r16 regressions):
// wave-matched flags, fa/fb poll, sc1 MALL h relay, one-asm-node h-fetch,
// xq in tail with vmcnt(0), f32 c-state in registers, fused xproj + u16
// group flags, emb_gather prepass (also zeroes the 266 KB scan region).
//
// Block (dir=bid>>6, kb=bid&63) owns 8 hidden units as 32 permuted gate cols:
//   tile t4 in {0,1}, lane col c in [0,16): gate g = c&3, unit jj = 2*(c>>2)+t4
//   orig Wih/Whh row = g*512 + kb*8 + jj.

typedef float  f32x4  __attribute__((ext_vector_type(4)));
typedef __bf16 bf16x8 __attribute__((ext_vector_type(8)));
typedef __bf16 bf16;

#define HB_OFF   ((size_t)0)        // 4 x [64 x 512] bf16 = 262144 B
#define FLAG_OFF ((size_t)262144)   // 512 x u32 = 2048 B
#define XF_OFF   ((size_t)264192)   // 1024 x u16 xproj group flags (new path)
                                    // (same bytes are ZROW in the legacy path)
#define WS_ZERO_BYTES ((size_t)266240)
#define XP_OFF   ((size_t)266240)                 // 128 blk*128 s*2048 f32
#define XP_BYTES ((size_t)134217728)
#define EBF_OFF  (XP_OFF + XP_BYTES)              // 8192 rows * 512 bf16
#define EBF_BYTES ((size_t)8388608)
#define WS_NEED  (EBF_OFF + EBF_BYTES)            // 142,872,576 B (unchanged)

__device__ __forceinline__ float sigmoidf_(float x) {
    return 1.0f / (1.0f + __expf(-x));
}
__device__ __forceinline__ float tanhf_(float x) {
    return 2.0f * sigmoidf_(2.0f * x) - 1.0f;
}
__device__ __forceinline__ bf16x8 cvt8(const float* p) {
    float4 a = *(const float4*)p;
    float4 b = *(const float4*)(p + 4);
    bf16x8 r;
    r[0] = (bf16)a.x; r[1] = (bf16)a.y; r[2] = (bf16)a.z; r[3] = (bf16)a.w;
    r[4] = (bf16)b.x; r[5] = (bf16)b.y; r[6] = (bf16)b.z; r[7] = (bf16)b.w;
    return r;
}
__device__ __forceinline__ bf16x8 cvt8v(uint4 u0, uint4 u1) {
    float4 a = __builtin_bit_cast(float4, u0);
    float4 b = __builtin_bit_cast(float4, u1);
    bf16x8 r;
    r[0] = (bf16)a.x; r[1] = (bf16)a.y; r[2] = (bf16)a.z; r[3] = (bf16)a.w;
    r[4] = (bf16)b.x; r[5] = (bf16)b.y; r[6] = (bf16)b.z; r[7] = (bf16)b.w;
    return r;
}
__device__ __forceinline__ void store4_sc1(float* p, f32x4 v) {
    asm volatile("global_store_dwordx4 %0, %1, off sc1"
                 :: "v"((unsigned long long)p), "v"(v) : "memory");
}
__device__ __forceinline__ void wait_xf(unsigned long long a) {
    for (;;) {
        unsigned v;
        asm volatile("global_load_ushort %0, %1, off sc1\n\t"
                     "s_waitcnt vmcnt(0)"
                     : "=&v"(v) : "v"(a) : "memory");
        if (v != 0) break;
        __builtin_amdgcn_s_sleep(2);
    }
}

__global__ __launch_bounds__(256) void init_ws_legacy(unsigned long long* __restrict__ w) {
    const size_t i = (size_t)blockIdx.x * 256 + threadIdx.x;
    if (i < WS_ZERO_BYTES / 8) w[i] = 0ull;
}

// ---- pre-pass: gather + f32->bf16 embedding rows; pad rows zeroed.
// Blocks 0..129 also zero the 266 KB scan region (hbuf + relay flags + XF).
__global__ __launch_bounds__(256) void emb_gather(
    const int* __restrict__ data, const float* __restrict__ table,
    bf16* __restrict__ ebf, unsigned long long* __restrict__ wz)
{
    const int bid = blockIdx.x, tid = threadIdx.x;
    if (bid < 130) {                                // 130*256*8 = 266240 B
        wz[(size_t)bid * 256 + tid] = 0ull;
    }
    const int wave = tid >> 6, lane = tid & 63;
    const int rr = bid * 4 + wave;                  // 0..8191 = t*64+b
    const int qv = data[rr];
    bf16x8 v;
    if (qv >= 0) {
        v = cvt8(table + (size_t)qv * 512 + lane * 8);
    } else {
#pragma unroll
        for (int i = 0; i < 8; ++i) v[i] = (bf16)0.f;
    }
    *(bf16x8*)(ebf + (size_t)rr * 512 + lane * 8) = v;
}

// ---- fused kernel: scan role (bid<128) + xproj role (bid>=128) ----
__global__ __launch_bounds__(256, 1) void fused_scan(
    const float* __restrict__ mask,
    const float* __restrict__ whh_f, const float* __restrict__ whh_b,
    const float* __restrict__ bih_f, const float* __restrict__ bhh_f,
    const float* __restrict__ bih_b, const float* __restrict__ bhh_b,
    const float* __restrict__ wih_f, const float* __restrict__ wih_b,
    const bf16* __restrict__ ebf,
    float* __restrict__ xp,
    bf16* __restrict__ hbuf,
    unsigned* __restrict__ flags,
    unsigned short* __restrict__ xf,
    float* __restrict__ out)
{
    __shared__ bf16 sM[4096 * 8];      // 64 KB; scan role uses first 32 KB

    const int tid = threadIdx.x, bid = blockIdx.x;
    const int wave = tid >> 6, lane = tid & 63;
    const int c = lane & 15, q = lane >> 4;

    if (bid >= 128) {
        // ================= xproj role =================
        // sh-MAJOR decomposition: xbid = sh*64 + dir*32 + cc, so bids
        // 128..191 (first resident cohort) are the sh=0 producers for BOTH
        // dirs. Work per (dir,cc,sh) identical to r13: xp for kb=2cc,2cc+1,
        // steps sh*8..sh*8+7, kc-ascending MFMA (bitwise-identical numerics).
        const int xbid = bid - 128;
        const int sh = xbid >> 6, dir = (xbid >> 5) & 1, cc = xbid & 31;
        const float* wih = dir ? wih_b : wih_f;

        for (int e = tid; e < 4096; e += 256) {
            const int ec = e & 15, eq = (e >> 4) & 3, et = (e >> 6) & 3, ekc = e >> 8;
            const int kbx = 2 * cc + (et >> 1), t4x = et & 1;
            const size_t orig = (size_t)((ec & 3) * 512 + kbx * 8 + 2 * (ec >> 2) + t4x);
            *(bf16x8*)(&sM[e * 8]) = cvt8(&wih[orig * 512 + ekc * 32 + eq * 8]);
        }
        __syncthreads();

        const int hrow = 16 * wave + c;
        const f32x4 zz = {0.f, 0.f, 0.f, 0.f};
        const size_t flin = (size_t)wave * 512 + (q * 16 + c) * 8;

        for (int s0 = 0; s0 < 8; ++s0) {
            const int s = sh * 8 + s0;
            const int tt = dir ? (127 - s) : s;
            const bf16* arow = ebf + (size_t)(tt * 64 + hrow) * 512;
            uint4 af[16];
#pragma unroll
            for (int kc = 0; kc < 16; ++kc)
                af[kc] = *(const uint4*)(arow + kc * 32 + q * 8);

            f32x4 acc0 = zz, acc1 = zz, acc2 = zz, acc3 = zz;
#pragma unroll
            for (int kc = 0; kc < 16; ++kc) {
                const bf16x8 a = __builtin_bit_cast(bf16x8, af[kc]);
                acc0 = __builtin_amdgcn_mfma_f32_16x16x32_bf16(
                    a, *(const bf16x8*)(&sM[(kc * 256 +   0 + q * 16 + c) * 8]), acc0, 0, 0, 0);
                acc1 = __builtin_amdgcn_mfma_f32_16x16x32_bf16(
                    a, *(const bf16x8*)(&sM[(kc * 256 +  64 + q * 16 + c) * 8]), acc1, 0, 0, 0);
                acc2 = __builtin_amdgcn_mfma_f32_16x16x32_bf16(
                    a, *(const bf16x8*)(&sM[(kc * 256 + 128 + q * 16 + c) * 8]), acc2, 0, 0, 0);
                acc3 = __builtin_amdgcn_mfma_f32_16x16x32_bf16(
                    a, *(const bf16x8*)(&sM[(kc * 256 + 192 + q * 16 + c) * 8]), acc3, 0, 0, 0);
            }
            const size_t r0 = ((size_t)(dir * 64 + 2 * cc)     * 128 + s) * 2048 + flin;
            const size_t r1 = ((size_t)(dir * 64 + 2 * cc + 1) * 128 + s) * 2048 + flin;
            store4_sc1(&xp[r0],     acc0);      // kb=2cc,  t4=0
            store4_sc1(&xp[r0 + 4], acc1);      // kb=2cc,  t4=1
            store4_sc1(&xp[r1],     acc2);      // kb=2cc+1,t4=0
            store4_sc1(&xp[r1 + 4], acc3);      // kb=2cc+1,t4=1
        }
        __builtin_amdgcn_s_waitcnt(0x0F70);     // this wave's sc1 stores acked
        __syncthreads();                        // all 4 waves acked
        if (tid == 0) {
            const unsigned long long fa =
                (unsigned long long)&xf[(dir * 32 + cc) * 16 + sh];
            asm volatile("global_store_short %0, %1, off sc1"
                         :: "v"(fa), "v"(1u) : "memory");
        }
        return;
    }

    // ================= scan role (r13 protocol + activate-then-shuffle) =====
    const int dir = bid >> 6, kb = bid & 63;
    const int g = c & 3;

    const float* whh = dir ? whh_b : whh_f;
    const float* bih = dir ? bih_b : bih_f;
    const float* bhh = dir ? bhh_b : bhh_f;

    for (int e = tid; e < 2048; e += 256) {
        const int ec = e & 15, eq = (e >> 4) & 3, et = (e >> 6) & 1, ekc = e >> 7;
        const size_t orig = (size_t)((ec & 3) * 512 + kb * 8 + 2 * (ec >> 2) + et);
        *(bf16x8*)(&sM[e * 8]) = cvt8(&whh[orig * 512 + ekc * 32 + eq * 8]);
    }
    float bias_v[2];
#pragma unroll
    for (int t4 = 0; t4 < 2; ++t4) {
        const int orig = g * 512 + kb * 8 + 2 * (c >> 2) + t4;
        bias_v[t4] = bih[orig] + bhh[orig];
    }

    float cst[2][4] = {{0.f, 0.f, 0.f, 0.f}, {0.f, 0.f, 0.f, 0.f}};
    const int hrow = 16 * wave + c;
    const int myflag = dir * 256 + wave * 64 + kb;
    const int fidx   = dir * 256 + wave * 64 + lane;
    const f32x4 zz = {0.f, 0.f, 0.f, 0.f};
    __syncthreads();                    // sM(=sW) ready; no syncs after this

    // xproj group-flag base for this block's (dir, cc=kb>>1)
    const unsigned long long xfb =
        (unsigned long long)(xf + ((size_t)(dir * 32 + (kb >> 1)) * 16));

    // prologue: wait group 0, then x-gate fragment + mask for step 0
    const float* xpb = xp + (size_t)bid * 128 * 2048
                          + (size_t)wave * 512 + (q * 16 + c) * 8;
    wait_xf(xfb);
    float4 xq0, xq1;
    {
        uint4 u0, u1;
        const unsigned long long xa = (unsigned long long)xpb;
        asm volatile("global_load_dwordx4 %0, %2, off sc1\n\t"
                     "global_load_dwordx4 %1, %2, off offset:16 sc1\n\t"
                     "s_waitcnt vmcnt(0)"
                     : "=&v"(u0), "=&v"(u1) : "v"(xa) : "memory");
        xq0 = __builtin_bit_cast(float4, u0);
        xq1 = __builtin_bit_cast(float4, u1);
    }
    float4 mv;
    {
        const int tt0 = dir ? 127 : 0;
        mv = *(const float4*)(&mask[tt0 * 64 + 16 * wave + 4 * q]);
    }

    for (int s = 0; s < 128; ++s) {
        const int tt = dir ? (127 - s) : s;

        // ---- wait: the 64 wave-matched producer waves completed step s-1 ----
        const unsigned tgt = (unsigned)s;
        unsigned fa = __hip_atomic_load(flags + fidx, __ATOMIC_RELAXED, __HIP_MEMORY_SCOPE_AGENT);
        unsigned fb = __hip_atomic_load(flags + fidx, __ATOMIC_RELAXED, __HIP_MEMORY_SCOPE_AGENT);
        for (;;) {
            if (__all(fa >= tgt)) break;
            fa = fb;
            fb = __hip_atomic_load(flags + fidx, __ATOMIC_RELAXED, __HIP_MEMORY_SCOPE_AGENT);
        }
        __asm__ volatile("" ::: "memory");   // keep h-loads below the poll

        const bf16* hb = hbuf + (size_t)(dir * 2 + (s & 1)) * (64 * 512);
        bf16*       hw = hbuf + (size_t)(dir * 2 + ((s + 1) & 1)) * (64 * 512);

        // ---- h A-fragments: ONE asm node = 16 sc1 dwordx4 + vmcnt(0) ----
        const unsigned long long ha =
            (unsigned long long)hb + (unsigned)(hrow * 1024 + q * 16);
        uint4 af[16];
        asm volatile(
            "global_load_dwordx4 %0,  %16, off sc1\n\t"
            "global_load_dwordx4 %1,  %16, off offset:64   sc1\n\t"
            "global_load_dwordx4 %2,  %16, off offset:128  sc1\n\t"
            "global_load_dwordx4 %3,  %16, off offset:192  sc1\n\t"
            "global_load_dwordx4 %4,  %16, off offset:256  sc1\n\t"
            "global_load_dwordx4 %5,  %16, off offset:320  sc1\n\t"
            "global_load_dwordx4 %6,  %16, off offset:384  sc1\n\t"
            "global_load_dwordx4 %7,  %16, off offset:448  sc1\n\t"
            "global_load_dwordx4 %8,  %16, off offset:512  sc1\n\t"
            "global_load_dwordx4 %9,  %16, off offset:576  sc1\n\t"
            "global_load_dwordx4 %10, %16, off offset:640  sc1\n\t"
            "global_load_dwordx4 %11, %16, off offset:704  sc1\n\t"
            "global_load_dwordx4 %12, %16, off offset:768  sc1\n\t"
            "global_load_dwordx4 %13, %16, off offset:832  sc1\n\t"
            "global_load_dwordx4 %14, %16, off offset:896  sc1\n\t"
            "global_load_dwordx4 %15, %16, off offset:960  sc1\n\t"
            "s_waitcnt vmcnt(0)"
            : "=&v"(af[0]),  "=&v"(af[1]),  "=&v"(af[2]),  "=&v"(af[3]),
              "=&v"(af[4]),  "=&v"(af[5]),  "=&v"(af[6]),  "=&v"(af[7]),
              "=&v"(af[8]),  "=&v"(af[9]),  "=&v"(af[10]), "=&v"(af[11]),
              "=&v"(af[12]), "=&v"(af[13]), "=&v"(af[14]), "=&v"(af[15])
            : "v"(ha)
            : "memory");

        f32x4 acc0 = zz, acc1 = zz;
#pragma unroll
        for (int kc = 0; kc < 16; ++kc) {
            const bf16x8 a  = __builtin_bit_cast(bf16x8, af[kc]);
            const bf16x8 b0 = *(const bf16x8*)(&sM[(kc * 128 + q * 16 + c) * 8]);
            const bf16x8 b1 = *(const bf16x8*)(&sM[(kc * 128 + 64 + q * 16 + c) * 8]);
            acc0 = __builtin_amdgcn_mfma_f32_16x16x32_bf16(a, b0, acc0, 0, 0, 0);
            acc1 = __builtin_amdgcn_mfma_f32_16x16x32_bf16(a, b1, acc1, 0, 0, 0);
        }

        // ---- epilogue: C/D layout col=lane&15, row=q*4+r ----
        // Activate-then-shuffle: lane g applies its OWN gate's activation
        // first (gate 2 = tanh via the 2*sig(2x)-1 identity, branchless ->
        // bitwise identical), then the quad shuffle moves ACTIVATED values.
        // Transcendental evals: 5 -> 2 per (r,t4) pair.
        unsigned* hw32 = (unsigned*)hw;
        float hreg[4][2];
        const bool isg = (g == 2);
#pragma unroll
        for (int r = 0; r < 4; ++r) {
            const int b_ = 16 * wave + 4 * q + r;
            const float m = (&mv.x)[r];
            float hv01[2];
#pragma unroll
            for (int t4 = 0; t4 < 2; ++t4) {
                const float v = (t4 ? acc1[r] : acc0[r])
                              + (t4 ? (&xq1.x)[r] : (&xq0.x)[r]) + bias_v[t4];
                float a_ = sigmoidf_(isg ? 2.0f * v : v);
                a_ = isg ? 2.0f * a_ - 1.0f : a_;       // == tanhf_(v) for g==2
                const float a1 = __shfl_xor(a_, 1);
                const float a2 = __shfl_xor(a_, 2);
                const float a3 = __shfl_xor(a_, 3);
                const float ti = (g == 0) ? a_ : (g == 1) ? a1 : (g == 2) ? a2 : a3;
                const float tf = (g == 0) ? a1 : (g == 1) ? a_ : (g == 2) ? a3 : a2;
                const float tG = (g == 0) ? a2 : (g == 1) ? a3 : (g == 2) ? a_ : a1;
                const float to = (g == 0) ? a3 : (g == 1) ? a2 : (g == 2) ? a1 : a_;
                const float cn = tf * cst[t4][r] + ti * tG;
                float hv       = to * tanhf_(cn);
                cst[t4][r] = cn * m;
                hv *= m;
                hv01[t4] = hv;
            }
            hreg[r][0] = hv01[0]; hreg[r][1] = hv01[1];
            if (g == 0) {                   // packed 2xbf16 -> one u32 sc1 store
                const unsigned u =
                    (unsigned)__builtin_bit_cast(unsigned short, (bf16)hv01[0]) |
                    ((unsigned)__builtin_bit_cast(unsigned short, (bf16)hv01[1]) << 16);
                __hip_atomic_store(hw32 + b_ * 256 + kb * 4 + (c >> 2), u,
                                   __ATOMIC_RELAXED, __HIP_MEMORY_SCOPE_AGENT);
            }
        }

        // release: all h sc1-stores acked at MALL before flag store
        __asm__ volatile("" ::: "memory");
        __builtin_amdgcn_s_waitcnt(0x0F70);  // vmcnt(0)
        if (lane == 0)
            __hip_atomic_store(flags + myflag, (unsigned)(s + 1),
                               __ATOMIC_RELAXED, __HIP_MEMORY_SCOPE_AGENT);

        // ---- step tail (hidden behind other blocks' consumption) ----
        if (g == 0) {
            const int j2 = dir * 512 + kb * 8 + 2 * (c >> 2);
#pragma unroll
            for (int r = 0; r < 4; ++r) {
                const int b_ = 16 * wave + 4 * q + r;
                float2 o2; o2.x = hreg[r][0]; o2.y = hreg[r][1];
                *(float2*)(&out[(size_t)(tt * 64 + b_) * 1024 + j2]) = o2;
            }
        }
        if (s < 127) {
            if (((s + 1) & 7) == 0)                 // new 8-step group
                wait_xf(xfb + (unsigned)(((s + 1) >> 3) * 2));
            uint4 u0, u1;
            const unsigned long long xa =
                (unsigned long long)(xpb + (size_t)(s + 1) * 2048);
            asm volatile("global_load_dwordx4 %0, %2, off sc1\n\t"
                         "global_load_dwordx4 %1, %2, off offset:16 sc1\n\t"
                         "s_waitcnt vmcnt(0)"
                         : "=&v"(u0), "=&v"(u1) : "v"(xa) : "memory");
            xq0 = __builtin_bit_cast(float4, u0);
            xq1 = __builtin_bit_cast(float4, u1);
            const int tt_n = dir ? (126 - s) : (s + 1);
            mv  = *(const float4*)(&mask[tt_n * 64 + 16 * wave + 4 * q]);
        }
    }
}

// ================= verbatim round-9 fallback (ws too small) =================
__global__ __launch_bounds__(256, 1) void lstm_scan_legacy(
    const int*   __restrict__ data,
    const float* __restrict__ mask,
    const float* __restrict__ table,
    const float* __restrict__ wih_f, const float* __restrict__ whh_f,
    const float* __restrict__ bih_f, const float* __restrict__ bhh_f,
    const float* __restrict__ wih_b, const float* __restrict__ whh_b,
    const float* __restrict__ bih_b, const float* __restrict__ bhh_b,
    bf16* __restrict__ hbuf,
    unsigned* __restrict__ flags,
    const float* __restrict__ zrow,
    float* __restrict__ out)
{
    __shared__ bf16 sW[2048 * 8];
    __shared__ bf16 sV[2048 * 8];

    const int tid = threadIdx.x, bid = blockIdx.x;
    const int dir = bid >> 6, kb = bid & 63;
    const int wave = tid >> 6, lane = tid & 63;
    const int c = lane & 15, q = lane >> 4, g = c & 3;

    const float* wih = dir ? wih_b : wih_f;
    const float* whh = dir ? whh_b : whh_f;
    const float* bih = dir ? bih_b : bih_f;
    const float* bhh = dir ? bhh_b : bhh_f;

    for (int e = tid; e < 2048; e += 256) {
        const int ec = e & 15, eq = (e >> 4) & 3, et = (e >> 6) & 1, ekc = e >> 7;
        const size_t orig = (size_t)((ec & 3) * 512 + kb * 8 + 2 * (ec >> 2) + et);
        const size_t off = orig * 512 + ekc * 32 + eq * 8;
        *(bf16x8*)(&sW[e * 8]) = cvt8(&whh[off]);
        *(bf16x8*)(&sV[e * 8]) = cvt8(&wih[off]);
    }
    float bias_v[2];
#pragma unroll
    for (int t4 = 0; t4 < 2; ++t4) {
        const int orig = g * 512 + kb * 8 + 2 * (c >> 2) + t4;
        bias_v[t4] = bih[orig] + bhh[orig];
    }

    float cst[2][4] = {{0.f, 0.f, 0.f, 0.f}, {0.f, 0.f, 0.f, 0.f}};
    const int hrow = 16 * wave + c;
    const int myflag = dir * 256 + kb * 4 + wave;
    const int fbase = dir * 256;
    const f32x4 zz = {0.f, 0.f, 0.f, 0.f};
    __syncthreads();

    uint4 xe[32];
    float4 mv;
    int qv_n;
    {
        const int tt0 = dir ? 127 : 0;
        const int qv0 = data[tt0 * 64 + hrow];
        mv = *(const float4*)(&mask[tt0 * 64 + 16 * wave + 4 * q]);
        const float* erow = (qv0 >= 0) ? (table + (size_t)qv0 * 512) : zrow;
#pragma unroll
        for (int kc = 0; kc < 16; ++kc) {
            xe[2 * kc]     = *(const uint4*)(erow + kc * 32 + q * 8);
            xe[2 * kc + 1] = *(const uint4*)(erow + kc * 32 + q * 8 + 4);
        }
        const int tt1 = dir ? 126 : 1;
        qv_n = data[tt1 * 64 + hrow];
    }

    for (int s = 0; s < 128; ++s) {
        const int tt = dir ? (127 - s) : s;

        f32x4 accx0 = zz, accx1 = zz;
#pragma unroll
        for (int kc = 0; kc < 16; ++kc) {
            const bf16x8 e  = cvt8v(xe[2 * kc], xe[2 * kc + 1]);
            const bf16x8 b0 = *(const bf16x8*)(&sV[(kc * 128 + q * 16 + c) * 8]);
            const bf16x8 b1 = *(const bf16x8*)(&sV[(kc * 128 + 64 + q * 16 + c) * 8]);
            accx0 = __builtin_amdgcn_mfma_f32_16x16x32_bf16(e, b0, accx0, 0, 0, 0);
            accx1 = __builtin_amdgcn_mfma_f32_16x16x32_bf16(e, b1, accx1, 0, 0, 0);
        }

        const unsigned tgt = (unsigned)s;
        for (;;) {
            const unsigned a0 = __hip_atomic_load(flags + fbase + lane,       __ATOMIC_RELAXED, __HIP_MEMORY_SCOPE_AGENT);
            const unsigned a1 = __hip_atomic_load(flags + fbase + 64  + lane, __ATOMIC_RELAXED, __HIP_MEMORY_SCOPE_AGENT);
            const unsigned a2 = __hip_atomic_load(flags + fbase + 128 + lane, __ATOMIC_RELAXED, __HIP_MEMORY_SCOPE_AGENT);
            const unsigned a3 = __hip_atomic_load(flags + fbase + 192 + lane, __ATOMIC_RELAXED, __HIP_MEMORY_SCOPE_AGENT);
            if (__all(a0 >= tgt && a1 >= tgt && a2 >= tgt && a3 >= tgt)) break;
            __builtin_amdgcn_s_sleep(1);
        }
        __asm__ volatile("" ::: "memory");

        const bf16* hb = hbuf + (size_t)(dir * 2 + (s & 1)) * (64 * 512);
        bf16*       hw = hbuf + (size_t)(dir * 2 + ((s + 1) & 1)) * (64 * 512);

        const unsigned long long ha =
            (unsigned long long)hb + (unsigned)(hrow * 1024 + q * 16);
        uint4 af[16];
        asm volatile(
            "global_load_dwordx4 %0,  %16, off sc1\n\t"
            "global_load_dwordx4 %1,  %16, off offset:64   sc1\n\t"
            "global_load_dwordx4 %2,  %16, off offset:128  sc1\n\t"
            "global_load_dwordx4 %3,  %16, off offset:192  sc1\n\t"
            "global_load_dwordx4 %4,  %16, off offset:256  sc1\n\t"
            "global_load_dwordx4 %5,  %16, off offset:320  sc1\n\t"
            "global_load_dwordx4 %6,  %16, off offset:384  sc1\n\t"
            "global_load_dwordx4 %7,  %16, off offset:448  sc1\n\t"
            "global_load_dwordx4 %8,  %16, off offset:512  sc1\n\t"
            "global_load_dwordx4 %9,  %16, off offset:576  sc1\n\t"
            "global_load_dwordx4 %10, %16, off offset:640  sc1\n\t"
            "global_load_dwordx4 %11, %16, off offset:704  sc1\n\t"
            "global_load_dwordx4 %12, %16, off offset:768  sc1\n\t"
            "global_load_dwordx4 %13, %16, off offset:832  sc1\n\t"
            "global_load_dwordx4 %14, %16, off offset:896  sc1\n\t"
            "global_load_dwordx4 %15, %16, off offset:960  sc1\n\t"
            "s_waitcnt vmcnt(0)"
            : "=&v"(af[0]),  "=&v"(af[1]),  "=&v"(af[2]),  "=&v"(af[3]),
              "=&v"(af[4]),  "=&v"(af[5]),  "=&v"(af[6]),  "=&v"(af[7]),
              "=&v"(af[8]),  "=&v"(af[9]),  "=&v"(af[10]), "=&v"(af[11]),
              "=&v"(af[12]), "=&v"(af[13]), "=&v"(af[14]), "=&v"(af[15])
            : "v"(ha)
            : "memory");

        f32x4 acc0 = zz, acc1 = zz;
#pragma unroll
        for (int kc = 0; kc < 16; ++kc) {
            const bf16x8 a  = __builtin_bit_cast(bf16x8, af[kc]);
            const bf16x8 b0 = *(const bf16x8*)(&sW[(kc * 128 + q * 16 + c) * 8]);
            const bf16x8 b1 = *(const bf16x8*)(&sW[(kc * 128 + 64 + q * 16 + c) * 8]);
            acc0 = __builtin_amdgcn_mfma_f32_16x16x32_bf16(a, b0, acc0, 0, 0, 0);
            acc1 = __builtin_amdgcn_mfma_f32_16x16x32_bf16(a, b1, acc1, 0, 0, 0);
        }

        unsigned* hw32 = (unsigned*)hw;
        float hreg[4][2];
#pragma unroll
        for (int r = 0; r < 4; ++r) {
            const int b_ = 16 * wave + 4 * q + r;
            const float m = (&mv.x)[r];
            float hv01[2];
#pragma unroll
            for (int t4 = 0; t4 < 2; ++t4) {
                float v = (t4 ? acc1[r] : acc0[r]) + (t4 ? accx1[r] : accx0[r]) + bias_v[t4];
                const float v1 = __shfl_xor(v, 1);
                const float v2 = __shfl_xor(v, 2);
                const float v3 = __shfl_xor(v, 3);
                const float gi = (g == 0) ? v  : (g == 1) ? v1 : (g == 2) ? v2 : v3;
                const float gf = (g == 0) ? v1 : (g == 1) ? v  : (g == 2) ? v3 : v2;
                const float gG = (g == 0) ? v2 : (g == 1) ? v3 : (g == 2) ? v  : v1;
                const float go = (g == 0) ? v3 : (g == 1) ? v2 : (g == 2) ? v1 : v;
                const float cn = sigmoidf_(gf) * cst[t4][r] + sigmoidf_(gi) * tanhf_(gG);
                float hv       = sigmoidf_(go) * tanhf_(cn);
                cst[t4][r] = cn * m;
                hv *= m;
                hv01[t4] = hv;
            }
            hreg[r][0] = hv01[0]; hreg[r][1] = hv01[1];
            if (g == 0) {
                const unsigned u =
                    (unsigned)__builtin_bit_cast(unsigned short, (bf16)hv01[0]) |
                    ((unsigned)__builtin_bit_cast(unsigned short, (bf16)hv01[1]) << 16);
                __hip_atomic_store(hw32 + b_ * 256 + kb * 4 + (c >> 2), u,
                                   __ATOMIC_RELAXED, __HIP_MEMORY_SCOPE_AGENT);
            }
        }

        __asm__ volatile("" ::: "memory");
        __builtin_amdgcn_s_waitcnt(0x0F70);
        if (lane == 0)
            __hip_atomic_store(flags + myflag, (unsigned)(s + 1),
                               __ATOMIC_RELAXED, __HIP_MEMORY_SCOPE_AGENT);

        if (g == 0) {
            const int j2 = dir * 512 + kb * 8 + 2 * (c >> 2);
#pragma unroll
            for (int r = 0; r < 4; ++r) {
                const int b_ = 16 * wave + 4 * q + r;
                float2 o2; o2.x = hreg[r][0]; o2.y = hreg[r][1];
                *(float2*)(&out[(size_t)(tt * 64 + b_) * 1024 + j2]) = o2;
            }
        }
        if (s < 127) {
            const int tt_n = dir ? (126 - s) : (s + 1);
            const float* erow = (qv_n >= 0) ? (table + (size_t)qv_n * 512) : zrow;
#pragma unroll
            for (int kc = 0; kc < 16; ++kc) {
                xe[2 * kc]     = *(const uint4*)(erow + kc * 32 + q * 8);
                xe[2 * kc + 1] = *(const uint4*)(erow + kc * 32 + q * 8 + 4);
            }
            mv = *(const float4*)(&mask[tt_n * 64 + 16 * wave + 4 * q]);
            if (s < 126) {
                const int tt_n2 = dir ? (125 - s) : (s + 2);
                qv_n = data[tt_n2 * 64 + hrow];
            }
        }
    }
}

extern "C" void kernel_launch(void* const* d_in, const int* in_sizes, int n_in,
                              void* d_out, int out_size, void* d_ws, size_t ws_size,
                              hipStream_t stream) {
    const int*   data  = (const int*)d_in[0];
    const float* mask  = (const float*)d_in[1];
    const float* table = (const float*)d_in[2];
    const float* wih_f = (const float*)d_in[3];
    const float* whh_f = (const float*)d_in[4];
    const float* bih_f = (const float*)d_in[5];
    const float* bhh_f = (const float*)d_in[6];
    const float* wih_b = (const float*)d_in[7];
    const float* whh_b = (const float*)d_in[8];
    const float* bih_b = (const float*)d_in[9];
    const float* bhh_b = (const float*)d_in[10];
    float* outp = (float*)d_out;

    char* ws = (char*)d_ws;
    bf16*     hbuf  = (bf16*)(ws + HB_OFF);
    unsigned* flagp = (unsigned*)(ws + FLAG_OFF);

    if (ws_size >= WS_NEED) {
        bf16*  ebf = (bf16*)(ws + EBF_OFF);
        float* xp  = (float*)(ws + XP_OFF);
        unsigned short* xf = (unsigned short*)(ws + XF_OFF);
        emb_gather<<<2048, 256, 0, stream>>>(data, table, ebf,
                                             (unsigned long long*)ws);
        fused_scan<<<1152, 256, 0, stream>>>(mask, whh_f, whh_b,
                                             bih_f, bhh_f, bih_b, bhh_b,
                                             wih_f, wih_b, ebf, xp,
                                             hbuf, flagp, xf, outp);
    } else {
        const float* zrow = (const float*)(ws + XF_OFF);   // legacy zrow bytes
        init_ws_legacy<<<(int)((WS_ZERO_BYTES / 8 + 255) / 256), 256, 0, stream>>>(
            (unsigned long long*)ws);
        lstm_scan_legacy<<<128, 256, 0, stream>>>(data, mask, table,
                                                  wih_f, whh_f, bih_f, bhh_f,
                                                  wih_b, whh_b, bih_b, bhh_b,
                                                  hbuf, flagp, zrow, outp);
    }
}